// Round 9
// baseline (421.642 us; speedup 1.0000x reference)
//
#include <hip/hip_runtime.h>
#include <hip/hip_bf16.h>
#include <stdint.h>

typedef __attribute__((ext_vector_type(8))) short short8;
typedef __attribute__((ext_vector_type(4))) float f32x4;
typedef __attribute__((ext_vector_type(16))) float f32x16;

#define SEQ 2048
#define DMODEL 1024
#define NH 16
#define DKH 64

__device__ __forceinline__ uint16_t f2b(float f) {
  uint32_t u = __float_as_uint(f);
  uint32_t r = (u + 0x7fff + ((u >> 16) & 1)) >> 16;
  return (uint16_t)r;
}
__device__ __forceinline__ float b2f(uint16_t u) {
  return __uint_as_float(((uint32_t)u) << 16);
}

__device__ __forceinline__ void gload16(const uint16_t* g, uint16_t* l) {
  __builtin_amdgcn_global_load_lds((const __attribute__((address_space(1))) void*)g,
                                   (__attribute__((address_space(3))) void*)l, 16, 0, 0);
}

// ---------------- cast x (f32 -> bf16), 4 elems/thread ----------------
__global__ __launch_bounds__(256) void k_castx(const float* __restrict__ x,
                                               uint16_t* __restrict__ xb) {
  int i = blockIdx.x * 256 + threadIdx.x;
  float4 v = reinterpret_cast<const float4*>(x)[i];
  uint16_t o[4] = {f2b(v.x), f2b(v.y), f2b(v.z), f2b(v.w)};
  reinterpret_cast<uint2*>(xb)[i] = *reinterpret_cast<uint2*>(o);
}

// ---------------- all weight cast+transposes in ONE kernel ----------------
__global__ __launch_bounds__(256) void k_tcast_all(
    const float* __restrict__ Wq, const float* __restrict__ Wk, const float* __restrict__ Wv,
    const float* __restrict__ Wo, const float* __restrict__ W1, const float* __restrict__ W2,
    uint16_t* __restrict__ wt_qkv, uint16_t* __restrict__ wt_o, uint16_t* __restrict__ wt_1,
    uint16_t* __restrict__ wt_2) {
  __shared__ float tile[32][33];
  const int id = blockIdx.x;
  const float* W;
  uint16_t* Wt;
  int K, N, bx, by;
  if (id < 4096) {
    int wsel = id >> 10, r = id & 1023;
    K = 1024; N = 1024; bx = r & 31; by = r >> 5;
    W = wsel == 0 ? Wq : (wsel == 1 ? Wk : (wsel == 2 ? Wv : Wo));
    Wt = wsel == 3 ? wt_o : wt_qkv + wsel * 1024 * 1024;
  } else if (id < 8192) {
    int r = id - 4096;
    K = 1024; N = 4096; bx = r & 127; by = r >> 7;
    W = W1; Wt = wt_1;
  } else {
    int r = id - 8192;
    K = 4096; N = 1024; bx = r & 31; by = r >> 5;
    W = W2; Wt = wt_2;
  }
  const int n0 = bx * 32, k0 = by * 32;
  const int tx = threadIdx.x & 31, ty = threadIdx.x >> 5;
#pragma unroll
  for (int i = 0; i < 32; i += 8)
    tile[ty + i][tx] = W[(size_t)(k0 + ty + i) * N + n0 + tx];
  __syncthreads();
#pragma unroll
  for (int i = 0; i < 32; i += 8)
    Wt[(size_t)(n0 + ty + i) * K + k0 + tx] = f2b(tile[tx][ty + i]);
}

// ---------------- V transpose per (b,h): [2048][64] -> [64][2048] bf16 ----------------
__global__ __launch_bounds__(256) void k_vtrans(const uint16_t* __restrict__ V,
                                                uint16_t* __restrict__ Vt) {
  __shared__ uint16_t tile[64][72];
  const int s0 = blockIdx.x * 64;
  const uint16_t* Vp = V + (size_t)blockIdx.y * SEQ * DKH;
  uint16_t* Vtp = Vt + (size_t)blockIdx.y * SEQ * DKH;
  const int t = threadIdx.x;
#pragma unroll
  for (int i = t; i < 512; i += 256) {
    int r = i >> 3, c8 = (i & 7) << 3;
    *reinterpret_cast<uint4*>(&tile[r][c8]) =
        *reinterpret_cast<const uint4*>(Vp + (size_t)(s0 + r) * DKH + c8);
  }
  __syncthreads();
#pragma unroll
  for (int i = t; i < 512; i += 256) {
    int d = i >> 3, s8 = (i & 7) << 3;
    uint16_t tmp[8];
#pragma unroll
    for (int j = 0; j < 8; ++j) tmp[j] = tile[s8 + j][d];
    *reinterpret_cast<uint4*>(Vtp + (size_t)d * SEQ + s0 + s8) = *reinterpret_cast<uint4*>(tmp);
  }
}

// ---------------- GEMM v2 (R6 schedule): 256-row tile, BK=64, 8 waves ------------------
#define MODE_QKV 0
#define MODE_RAW 1
#define MODE_RELU 2

template <int BN, int MODE>
__global__ __launch_bounds__(512, 2) void k_gemm2(
    const uint16_t* __restrict__ A, const uint16_t* __restrict__ Bt, int M, int N, int K,
    int nx, const float* __restrict__ bias0, const float* __restrict__ bias1,
    const float* __restrict__ bias2, uint16_t* __restrict__ ob0, uint16_t* __restrict__ ob1,
    uint16_t* __restrict__ ob2, float* __restrict__ of) {
  constexpr int ASZ = 256 * 64;
  constexpr int BSZ = BN * 64;
  __shared__ __align__(16) uint16_t lds[2 * (ASZ + BSZ)];
  uint16_t* const Abase = lds;
  uint16_t* const Bbase = lds + 2 * ASZ;
  constexpr int WN = (BN == 256) ? 4 : 2;
  constexpr int MREP = (BN == 256) ? 8 : 4;
  constexpr int NPH = (BN == 256) ? 4 : 2;
  const int o = blockIdx.x;
  const int chunk = gridDim.x >> 3;
  const int wg = (o & 7) * chunk + (o >> 3);
  const int brow = (wg / nx) << 8;
  const int bcol = (wg % nx) * BN;
  const int t = threadIdx.x;
  const int wid = t >> 6, l = t & 63, g = l >> 4, lr = l & 15;
  const int wr = wid / WN, wc = wid % WN;
  const int wrow = wr * (MREP * 16);
  const int wcol = wc * 64;

  const int srow = t >> 3;
  const int ss0 = (t & 7) ^ (srow & 7);
  const int ss1 = (t & 7) ^ ((srow + 64) & 7);

  auto stage_half = [&](const uint16_t* gsrc, int grow0, int kk, uint16_t* ldst) {
    gload16(gsrc + (size_t)(grow0 + srow) * K + kk + ss0 * 8, ldst + t * 8);
    gload16(gsrc + (size_t)(grow0 + srow + 64) * K + kk + ss1 * 8, ldst + 4096 + t * 8);
  };
  auto rdfrag = [&](const uint16_t* buf, int ar, int kk) -> short8 {
    int slot = ((kk << 2) + g) ^ (ar & 7);
    return *reinterpret_cast<const short8*>(buf + ar * 64 + slot * 8);
  };

  f32x4 acc[MREP][4] = {};
  const int nt = K >> 6;

  stage_half(A, brow, 0, Abase);
  stage_half(A, brow + 128, 0, Abase + 8192);
  stage_half(Bt, bcol, 0, Bbase);
  if (BN == 256) stage_half(Bt, bcol + 128, 0, Bbase + 8192);
  __syncthreads();

  for (int kt = 0; kt < nt; ++kt) {
    const int cur = kt & 1;
    const uint16_t* Ac = Abase + cur * ASZ;
    const uint16_t* Bc = Bbase + cur * BSZ;
    uint16_t* An = Abase + (cur ^ 1) * ASZ;
    uint16_t* Bn = Bbase + (cur ^ 1) * BSZ;
    const bool pf = (kt + 1 < nt);
    const int knx = (kt + 1) << 6;
#pragma unroll
    for (int q = 0; q < NPH; ++q) {
      const int mq = (BN == 256) ? (q >> 1) : 0;
      const int nq = (BN == 256) ? (q & 1) : q;
      short8 af[4][2], bf[2][2];
#pragma unroll
      for (int j = 0; j < 4; ++j)
#pragma unroll
        for (int kk = 0; kk < 2; ++kk)
          af[j][kk] = rdfrag(Ac, wrow + (mq * 4 + j) * 16 + lr, kk);
#pragma unroll
      for (int j = 0; j < 2; ++j)
#pragma unroll
        for (int kk = 0; kk < 2; ++kk)
          bf[j][kk] = rdfrag(Bc, wcol + (nq * 2 + j) * 16 + lr, kk);
      if (pf) {
        if (q == 0) {
          stage_half(A, brow, knx, An);
          stage_half(A, brow + 128, knx, An + 8192);
          if (BN == 128) stage_half(Bt, bcol, knx, Bn);
        }
        if (BN == 256 && q == 1) stage_half(Bt, bcol, knx, Bn);
        if (BN == 256 && q == 2) stage_half(Bt, bcol + 128, knx, Bn + 8192);
      }
      __builtin_amdgcn_s_barrier();
      __builtin_amdgcn_s_setprio(1);
#pragma unroll
      for (int j = 0; j < 4; ++j)
#pragma unroll
        for (int j2 = 0; j2 < 2; ++j2)
#pragma unroll
          for (int kk = 0; kk < 2; ++kk)
            acc[mq * 4 + j][nq * 2 + j2] = __builtin_amdgcn_mfma_f32_16x16x32_bf16(
                af[j][kk], bf[j2][kk], acc[mq * 4 + j][nq * 2 + j2], 0, 0, 0);
      __builtin_amdgcn_s_setprio(0);
      if (q == NPH - 1) {
        asm volatile("s_waitcnt vmcnt(0)" ::: "memory");
        __builtin_amdgcn_s_barrier();
        __builtin_amdgcn_sched_barrier(0);
      } else {
        __builtin_amdgcn_s_barrier();
      }
    }
  }

#pragma unroll
  for (int m = 0; m < MREP; ++m) {
#pragma unroll
    for (int n = 0; n < 4; ++n) {
#pragma unroll
      for (int qi = 0; qi < 4; ++qi) {
        int r = brow + wrow + m * 16 + g * 4 + qi;
        int c = bcol + wcol + n * 16 + lr;
        float v = acc[m][n][qi];
        if (MODE == MODE_QKV) {
          int which = c >> 10;
          int hd = c & 1023;
          const float* bp = which == 0 ? bias0 : (which == 1 ? bias1 : bias2);
          v += bp[hd];
          if (which == 0) v *= 0.1803368801f;  // 1/sqrt(dk) * log2(e)
          uint16_t* dst = which == 0 ? ob0 : (which == 1 ? ob1 : ob2);
          int b = r >> 11, tt = r & 2047;
          int h = hd >> 6, d = hd & 63;
          dst[((size_t)((b * NH + h) * SEQ + tt)) * DKH + d] = f2b(v);
        } else if (MODE == MODE_RELU) {
          v += bias0[c];
          v = fmaxf(v, 0.0f);
          ob0[(size_t)r * N + c] = f2b(v);
        } else {
          of[(size_t)r * N + c] = v;
        }
      }
    }
  }
}

// ---------------- attention v6: 64 q/wave, 256 q/block, grid 512, XCD-local ------------
__global__ __launch_bounds__(256) void k_attn(const uint16_t* __restrict__ Qb,
                                              const uint16_t* __restrict__ Kb,
                                              const uint16_t* __restrict__ Vtg,
                                              uint16_t* __restrict__ ctx) {
  __shared__ __align__(16) uint16_t Ks[2][64 * 64];
  __shared__ __align__(16) uint16_t Vs[2][64 * 64];
  __shared__ float l_arr[4][2][32];
  const int o = blockIdx.x;
  const int wg = (o & 7) * 64 + (o >> 3);  // 512 blocks, 64 per XCD
  const int qt = wg & 7;
  const int bh = wg >> 3;  // per XCD: bh in [8*(o&7), 8*(o&7)+8)
  const int b = bh >> 4, h = bh & 15;
  const uint16_t* Qp = Qb + (size_t)bh * SEQ * DKH;
  const uint16_t* Kp = Kb + (size_t)bh * SEQ * DKH;
  const uint16_t* Vp = Vtg + (size_t)bh * SEQ * DKH;  // [64][2048]
  const int t = threadIdx.x, w = t >> 6, l = t & 63;
  const int lo5 = l & 31, hh = l >> 5;
  const int qbase = qt * 256 + w * 64;

  short8 qf[2][4];
#pragma unroll
  for (int qb = 0; qb < 2; ++qb)
#pragma unroll
    for (int kc = 0; kc < 4; ++kc)
      qf[qb][kc] = *reinterpret_cast<const short8*>(
          Qp + (size_t)(qbase + qb * 32 + lo5) * DKH + kc * 16 + hh * 8);

  f32x16 oacc[2][2] = {};  // [qb][dblk]
  float lsum[2] = {0.f, 0.f};

  const int swz = ((l & 7) ^ ((l >> 3) & 7)) << 3;
  const int ci0 = w * 2, ci1 = w * 2 + 1;
  const int r0 = ci0 * 8 + (l >> 3), r1 = ci1 * 8 + (l >> 3);
  uint16_t* ldsK0 = &Ks[0][0] + ci0 * 512 + l * 8;
  uint16_t* ldsK1 = &Ks[0][0] + ci1 * 512 + l * 8;
  uint16_t* ldsV0 = &Vs[0][0] + ci0 * 512 + l * 8;
  uint16_t* ldsV1 = &Vs[0][0] + ci1 * 512 + l * 8;
  const uint16_t* gK0 = Kp + (size_t)r0 * DKH + swz;
  const uint16_t* gK1 = Kp + (size_t)r1 * DKH + swz;
  const uint16_t* gV0 = Vp + (size_t)r0 * SEQ + swz;
  const uint16_t* gV1 = Vp + (size_t)r1 * SEQ + swz;

  gload16(gK0, ldsK0);
  gload16(gK1, ldsK1);
  gload16(gV0, ldsV0);
  gload16(gV1, ldsV1);
  __syncthreads();

  for (int tile = 0; tile < 32; ++tile) {
    const int cur = tile & 1;
    if (tile < 31) {
      const int nxt = (cur ^ 1) * 4096;
      const size_t s0n = (size_t)(tile + 1) * 64;
      gload16(gK0 + s0n * DKH, ldsK0 + nxt);
      gload16(gK1 + s0n * DKH, ldsK1 + nxt);
      gload16(gV0 + s0n, ldsV0 + nxt);
      gload16(gV1 + s0n, ldsV1 + nxt);
    }
    const char* Kbuf = reinterpret_cast<const char*>(&Ks[cur][0]);
    const char* Vbuf = reinterpret_cast<const char*>(&Vs[cur][0]);

#pragma unroll
    for (int sblk = 0; sblk < 2; ++sblk) {
      short8 kf[4];
      const int krow = sblk * 32 + lo5;
      const int kxor = (krow & 7) << 4;
#pragma unroll
      for (int kc = 0; kc < 4; ++kc) {
        int cb = (kc * 32 + hh * 16) ^ kxor;
        kf[kc] = *reinterpret_cast<const short8*>(Kbuf + krow * 128 + cb);
      }
      short8 vf[2][2];
#pragma unroll
      for (int scl = 0; scl < 2; ++scl)
#pragma unroll
        for (int dblk = 0; dblk < 2; ++dblk) {
          int vrow = dblk * 32 + lo5;
          int cb = (sblk * 64 + scl * 32 + hh * 16) ^ ((vrow & 7) << 4);
          vf[scl][dblk] = *reinterpret_cast<const short8*>(Vbuf + vrow * 128 + cb);
        }

#pragma unroll
      for (int qb = 0; qb < 2; ++qb) {
        f32x16 sa = {};
        __builtin_amdgcn_s_setprio(1);
#pragma unroll
        for (int kc = 0; kc < 4; ++kc)
          sa = __builtin_amdgcn_mfma_f32_32x32x16_bf16(kf[kc], qf[qb][kc], sa, 0, 0, 0);
        __builtin_amdgcn_s_setprio(0);

        float p[16];
        float ls = 0.f;
#pragma unroll
        for (int r = 0; r < 16; ++r) {
          p[r] = __builtin_amdgcn_exp2f(sa[r]);
          ls += p[r];
        }
        lsum[qb] += ls;

        uint32_t clo[4], chi[4];
#pragma unroll
        for (int m = 0; m < 4; ++m) {
          asm("v_cvt_pk_bf16_f32 %0, %1, %2" : "=v"(clo[m]) : "v"(p[4 * m]), "v"(p[4 * m + 1]));
          asm("v_cvt_pk_bf16_f32 %0, %1, %2" : "=v"(chi[m]) : "v"(p[4 * m + 2]), "v"(p[4 * m + 3]));
        }

#pragma unroll
        for (int scl = 0; scl < 2; ++scl) {
          uint32_t a0 = clo[2 * scl], b0 = clo[2 * scl + 1];
          uint32_t a1 = chi[2 * scl], b1 = chi[2 * scl + 1];
          asm("v_permlane32_swap_b32 %0, %1" : "+v"(a0), "+v"(b0));
          asm("v_permlane32_swap_b32 %0, %1" : "+v"(a1), "+v"(b1));
          union {
            uint32_t u[4];
            short8 s;
          } pu;
          pu.u[0] = a0;
          pu.u[1] = a1;
          pu.u[2] = b0;
          pu.u[3] = b1;
          __builtin_amdgcn_s_setprio(1);
#pragma unroll
          for (int dblk = 0; dblk < 2; ++dblk)
            oacc[qb][dblk] =
                __builtin_amdgcn_mfma_f32_32x32x16_bf16(pu.s, vf[scl][dblk], oacc[qb][dblk], 0, 0, 0);
          __builtin_amdgcn_s_setprio(0);
        }
      }
    }
    __syncthreads();
  }

#pragma unroll
  for (int qb = 0; qb < 2; ++qb) {
    float full = lsum[qb] + __shfl_xor(lsum[qb], 32, 64);
    if (l < 32) l_arr[w][qb][lo5] = full;
  }
#pragma unroll
  for (int qb = 0; qb < 2; ++qb) {
#pragma unroll
    for (int r = 0; r < 16; ++r) {
      int q = (r & 3) + 8 * (r >> 2) + 4 * hh;
      float li = 1.0f / l_arr[w][qb][q];
      int rowg = b * SEQ + qbase + qb * 32 + q;
#pragma unroll
      for (int dblk = 0; dblk < 2; ++dblk) {
        int colg = h * DKH + dblk * 32 + lo5;
        ctx[(size_t)rowg * DMODEL + colg] = f2b(oacc[qb][dblk][r] * li);
      }
    }
  }
}

// ---------------- LayerNorm over (in + bias + res); res f32 or bf16 ----------------
template <bool WRITE_B, bool RESBF>
__global__ __launch_bounds__(256) void k_ln(const float* __restrict__ in,
                                            const float* __restrict__ bias,
                                            const void* __restrict__ res,
                                            const float* __restrict__ gam,
                                            const float* __restrict__ bet,
                                            float* __restrict__ outf,
                                            uint16_t* __restrict__ outb) {
  const int row = blockIdx.x;
  const int t = threadIdx.x, lane = t & 63, w = t >> 6;
  float4 v = reinterpret_cast<const float4*>(in + (size_t)row * DMODEL)[t];
  float4 bb0 = reinterpret_cast<const float4*>(bias)[t];
  float4 rr;
  if (RESBF) {
    uint2 ru = reinterpret_cast<const uint2*>((const uint16_t*)res + (size_t)row * DMODEL)[t];
    const uint16_t* rp = reinterpret_cast<const uint16_t*>(&ru);
    rr.x = b2f(rp[0]);
    rr.y = b2f(rp[1]);
    rr.z = b2f(rp[2]);
    rr.w = b2f(rp[3]);
  } else {
    rr = reinterpret_cast<const float4*>((const float*)res + (size_t)row * DMODEL)[t];
  }
  v.x += bb0.x + rr.x;
  v.y += bb0.y + rr.y;
  v.z += bb0.z + rr.z;
  v.w += bb0.w + rr.w;
  float s = v.x + v.y + v.z + v.w;
  float s2 = v.x * v.x + v.y * v.y + v.z * v.z + v.w * v.w;
#pragma unroll
  for (int off = 1; off < 64; off <<= 1) {
    s += __shfl_xor(s, off, 64);
    s2 += __shfl_xor(s2, off, 64);
  }
  __shared__ float rs[4], rq[4];
  if (lane == 0) {
    rs[w] = s;
    rq[w] = s2;
  }
  __syncthreads();
  float ts = rs[0] + rs[1] + rs[2] + rs[3];
  float tq = rq[0] + rq[1] + rq[2] + rq[3];
  const float inv = 1.0f / DMODEL;
  float mu = ts * inv;
  float var = tq * inv - mu * mu;
  float rstd = rsqrtf(var + 1e-5f);
  float4 gg = reinterpret_cast<const float4*>(gam)[t];
  float4 bb = reinterpret_cast<const float4*>(bet)[t];
  float4 y;
  y.x = (v.x - mu) * rstd * gg.x + bb.x;
  y.y = (v.y - mu) * rstd * gg.y + bb.y;
  y.z = (v.z - mu) * rstd * gg.z + bb.z;
  y.w = (v.w - mu) * rstd * gg.w + bb.w;
  if (WRITE_B) {
    uint16_t oo[4] = {f2b(y.x), f2b(y.y), f2b(y.z), f2b(y.w)};
    reinterpret_cast<uint2*>(outb)[(size_t)row * 256 + t] = *reinterpret_cast<uint2*>(oo);
  } else {
    reinterpret_cast<float4*>(outf)[(size_t)row * 256 + t] = y;
  }
}

extern "C" void kernel_launch(void* const* d_in, const int* in_sizes, int n_in, void* d_out,
                              int out_size, void* d_ws, size_t ws_size, hipStream_t stream) {
  const float* x = (const float*)d_in[0];
  const float* Wq = (const float*)d_in[1];
  const float* bq = (const float*)d_in[2];
  const float* Wk = (const float*)d_in[3];
  const float* bk = (const float*)d_in[4];
  const float* Wv = (const float*)d_in[5];
  const float* bv = (const float*)d_in[6];
  const float* Wo = (const float*)d_in[7];
  const float* bo = (const float*)d_in[8];
  const float* g1 = (const float*)d_in[9];
  const float* be1 = (const float*)d_in[10];
  const float* W1 = (const float*)d_in[11];
  const float* b1 = (const float*)d_in[12];
  const float* W2 = (const float*)d_in[13];
  const float* b2 = (const float*)d_in[14];
  const float* g2 = (const float*)d_in[15];
  const float* be2 = (const float*)d_in[16];

  char* ws = (char*)d_ws;
  size_t off = 0;
  auto alloc = [&](size_t bytes) {
    char* p = ws + off;
    off += (bytes + 255) & ~(size_t)255;
    return p;
  };
  uint16_t* wt_qkv = (uint16_t*)alloc(3072ull * 1024 * 2);
  uint16_t* wt_o = (uint16_t*)alloc(1024ull * 1024 * 2);
  uint16_t* wt_1 = (uint16_t*)alloc(4096ull * 1024 * 2);
  uint16_t* wt_2 = (uint16_t*)alloc(1024ull * 4096 * 2);
  uint16_t* xb = (uint16_t*)alloc(8192ull * 1024 * 2);  // x bf16; later aliased as ctx
  float* sum1 = (float*)alloc(8192ull * 1024 * 4);      // raw GEMM f32 out (Wo, then FFN2)
  uint16_t* vt = (uint16_t*)alloc(8192ull * 1024 * 2);  // V^T
  char* big = alloc(16777216ull + 67108864ull);         // QKV (48MB) -> x1b(16MB)+h(64MB)
  uint16_t* Qbuf = (uint16_t*)big;
  uint16_t* Kbuf = (uint16_t*)(big + 16777216ull);
  uint16_t* Vbuf = (uint16_t*)(big + 2 * 16777216ull);
  uint16_t* ctx = xb;
  uint16_t* x1b = (uint16_t*)big;                   // alias: Q dead after attention
  uint16_t* hbuf = (uint16_t*)(big + 16777216ull);  // alias: K,V dead after attention
  (void)ws_size;

  // 1. all weight prep in one launch
  k_tcast_all<<<12288, 256, 0, stream>>>(Wq, Wk, Wv, Wo, W1, W2, wt_qkv, wt_o, wt_1, wt_2);
  // 2. cast x
  k_castx<<<8192, 256, 0, stream>>>(x, xb);
  // 3. QKV projection, BN=128 -> 768 blocks (3 full dispatch waves)
  k_gemm2<128, MODE_QKV><<<768, 512, 0, stream>>>(
      xb, wt_qkv, 8192, 3072, 1024, 24, bq, bk, bv, Qbuf, Kbuf, Vbuf, nullptr);
  // 3.5 V transpose
  k_vtrans<<<dim3(32, 64), 256, 0, stream>>>(Vbuf, vt);
  // 4. attention -> ctx (64 q/wave, 512 blocks, XCD-local)
  k_attn<<<512, 256, 0, stream>>>(Qbuf, Kbuf, vt, ctx);
  // 5. Wo projection raw -> sum1
  k_gemm2<128, MODE_RAW><<<256, 512, 0, stream>>>(
      ctx, wt_o, 8192, 1024, 1024, 8, nullptr, nullptr, nullptr, nullptr, nullptr, nullptr, sum1);
  // 6. LN1(sum1 + bo + x) -> x1b (bf16 only)
  k_ln<true, false><<<8192, 256, 0, stream>>>(sum1, bo, x, g1, be1, nullptr, x1b);
  // 7. FFN1: relu(x1 @ W1 + b1) -> h bf16
  k_gemm2<256, MODE_RELU><<<512, 512, 0, stream>>>(
      x1b, wt_1, 8192, 4096, 1024, 16, b1, nullptr, nullptr, hbuf, nullptr, nullptr, nullptr);
  // 8. FFN2 raw -> sum1
  k_gemm2<128, MODE_RAW><<<256, 512, 0, stream>>>(
      hbuf, wt_2, 8192, 1024, 4096, 8, nullptr, nullptr, nullptr, nullptr, nullptr, nullptr, sum1);
  // 9. LN2(sum1 + b2 + x1b[bf16]) -> output (f32)
  k_ln<false, true><<<8192, 256, 0, stream>>>(sum1, b2, x1b, g2, be2, (float*)d_out, nullptr);
}

// Round 10
// 401.928 us; speedup vs baseline: 1.0490x; 1.0490x over previous
//
#include <hip/hip_runtime.h>
#include <hip/hip_bf16.h>
#include <stdint.h>

typedef __attribute__((ext_vector_type(8))) short short8;
typedef __attribute__((ext_vector_type(4))) float f32x4;
typedef __attribute__((ext_vector_type(16))) float f32x16;

#define SEQ 2048
#define DMODEL 1024
#define NH 16
#define DKH 64

__device__ __forceinline__ uint16_t f2b(float f) {
  uint32_t u = __float_as_uint(f);
  uint32_t r = (u + 0x7fff + ((u >> 16) & 1)) >> 16;
  return (uint16_t)r;
}
__device__ __forceinline__ float b2f(uint16_t u) {
  return __uint_as_float(((uint32_t)u) << 16);
}

__device__ __forceinline__ void gload16(const uint16_t* g, uint16_t* l) {
  __builtin_amdgcn_global_load_lds((const __attribute__((address_space(1))) void*)g,
                                   (__attribute__((address_space(3))) void*)l, 16, 0, 0);
}

// ---------------- cast x (f32 -> bf16), 4 elems/thread ----------------
__global__ __launch_bounds__(256) void k_castx(const float* __restrict__ x,
                                               uint16_t* __restrict__ xb) {
  int i = blockIdx.x * 256 + threadIdx.x;
  float4 v = reinterpret_cast<const float4*>(x)[i];
  uint16_t o[4] = {f2b(v.x), f2b(v.y), f2b(v.z), f2b(v.w)};
  reinterpret_cast<uint2*>(xb)[i] = *reinterpret_cast<uint2*>(o);
}

// ---------------- all weight cast+transposes in ONE kernel ----------------
__global__ __launch_bounds__(256) void k_tcast_all(
    const float* __restrict__ Wq, const float* __restrict__ Wk, const float* __restrict__ Wv,
    const float* __restrict__ Wo, const float* __restrict__ W1, const float* __restrict__ W2,
    uint16_t* __restrict__ wt_qkv, uint16_t* __restrict__ wt_o, uint16_t* __restrict__ wt_1,
    uint16_t* __restrict__ wt_2) {
  __shared__ float tile[32][33];
  const int id = blockIdx.x;
  const float* W;
  uint16_t* Wt;
  int K, N, bx, by;
  if (id < 4096) {
    int wsel = id >> 10, r = id & 1023;
    K = 1024; N = 1024; bx = r & 31; by = r >> 5;
    W = wsel == 0 ? Wq : (wsel == 1 ? Wk : (wsel == 2 ? Wv : Wo));
    Wt = wsel == 3 ? wt_o : wt_qkv + wsel * 1024 * 1024;
  } else if (id < 8192) {
    int r = id - 4096;
    K = 1024; N = 4096; bx = r & 127; by = r >> 7;
    W = W1; Wt = wt_1;
  } else {
    int r = id - 8192;
    K = 4096; N = 1024; bx = r & 31; by = r >> 5;
    W = W2; Wt = wt_2;
  }
  const int n0 = bx * 32, k0 = by * 32;
  const int tx = threadIdx.x & 31, ty = threadIdx.x >> 5;
#pragma unroll
  for (int i = 0; i < 32; i += 8)
    tile[ty + i][tx] = W[(size_t)(k0 + ty + i) * N + n0 + tx];
  __syncthreads();
#pragma unroll
  for (int i = 0; i < 32; i += 8)
    Wt[(size_t)(n0 + ty + i) * K + k0 + tx] = f2b(tile[tx][ty + i]);
}

// ---------------- V transpose per (b,h): [2048][64] -> [64][2048] bf16 ----------------
__global__ __launch_bounds__(256) void k_vtrans(const uint16_t* __restrict__ V,
                                                uint16_t* __restrict__ Vt) {
  __shared__ uint16_t tile[64][72];
  const int s0 = blockIdx.x * 64;
  const uint16_t* Vp = V + (size_t)blockIdx.y * SEQ * DKH;
  uint16_t* Vtp = Vt + (size_t)blockIdx.y * SEQ * DKH;
  const int t = threadIdx.x;
#pragma unroll
  for (int i = t; i < 512; i += 256) {
    int r = i >> 3, c8 = (i & 7) << 3;
    *reinterpret_cast<uint4*>(&tile[r][c8]) =
        *reinterpret_cast<const uint4*>(Vp + (size_t)(s0 + r) * DKH + c8);
  }
  __syncthreads();
#pragma unroll
  for (int i = t; i < 512; i += 256) {
    int d = i >> 3, s8 = (i & 7) << 3;
    uint16_t tmp[8];
#pragma unroll
    for (int j = 0; j < 8; ++j) tmp[j] = tile[s8 + j][d];
    *reinterpret_cast<uint4*>(Vtp + (size_t)d * SEQ + s0 + s8) = *reinterpret_cast<uint4*>(tmp);
  }
}

// ---------------- GEMM v2 (R6 schedule): 256-row tile, BK=64, 8 waves ------------------
#define MODE_QKV 0
#define MODE_RAW 1
#define MODE_RELU 2

template <int BN, int MODE>
__global__ __launch_bounds__(512, 2) void k_gemm2(
    const uint16_t* __restrict__ A, const uint16_t* __restrict__ Bt, int M, int N, int K,
    int nx, const float* __restrict__ bias0, const float* __restrict__ bias1,
    const float* __restrict__ bias2, uint16_t* __restrict__ ob0, uint16_t* __restrict__ ob1,
    uint16_t* __restrict__ ob2, float* __restrict__ of) {
  constexpr int ASZ = 256 * 64;
  constexpr int BSZ = BN * 64;
  __shared__ __align__(16) uint16_t lds[2 * (ASZ + BSZ)];
  uint16_t* const Abase = lds;
  uint16_t* const Bbase = lds + 2 * ASZ;
  constexpr int WN = (BN == 256) ? 4 : 2;
  constexpr int MREP = (BN == 256) ? 8 : 4;
  constexpr int NPH = (BN == 256) ? 4 : 2;
  const int o = blockIdx.x;
  const int chunk = gridDim.x >> 3;
  const int wg = (o & 7) * chunk + (o >> 3);
  const int brow = (wg / nx) << 8;
  const int bcol = (wg % nx) * BN;
  const int t = threadIdx.x;
  const int wid = t >> 6, l = t & 63, g = l >> 4, lr = l & 15;
  const int wr = wid / WN, wc = wid % WN;
  const int wrow = wr * (MREP * 16);
  const int wcol = wc * 64;

  const int srow = t >> 3;
  const int ss0 = (t & 7) ^ (srow & 7);
  const int ss1 = (t & 7) ^ ((srow + 64) & 7);

  auto stage_half = [&](const uint16_t* gsrc, int grow0, int kk, uint16_t* ldst) {
    gload16(gsrc + (size_t)(grow0 + srow) * K + kk + ss0 * 8, ldst + t * 8);
    gload16(gsrc + (size_t)(grow0 + srow + 64) * K + kk + ss1 * 8, ldst + 4096 + t * 8);
  };
  auto rdfrag = [&](const uint16_t* buf, int ar, int kk) -> short8 {
    int slot = ((kk << 2) + g) ^ (ar & 7);
    return *reinterpret_cast<const short8*>(buf + ar * 64 + slot * 8);
  };

  f32x4 acc[MREP][4] = {};
  const int nt = K >> 6;

  stage_half(A, brow, 0, Abase);
  stage_half(A, brow + 128, 0, Abase + 8192);
  stage_half(Bt, bcol, 0, Bbase);
  if (BN == 256) stage_half(Bt, bcol + 128, 0, Bbase + 8192);
  __syncthreads();

  for (int kt = 0; kt < nt; ++kt) {
    const int cur = kt & 1;
    const uint16_t* Ac = Abase + cur * ASZ;
    const uint16_t* Bc = Bbase + cur * BSZ;
    uint16_t* An = Abase + (cur ^ 1) * ASZ;
    uint16_t* Bn = Bbase + (cur ^ 1) * BSZ;
    const bool pf = (kt + 1 < nt);
    const int knx = (kt + 1) << 6;
#pragma unroll
    for (int q = 0; q < NPH; ++q) {
      const int mq = (BN == 256) ? (q >> 1) : 0;
      const int nq = (BN == 256) ? (q & 1) : q;
      short8 af[4][2], bf[2][2];
#pragma unroll
      for (int j = 0; j < 4; ++j)
#pragma unroll
        for (int kk = 0; kk < 2; ++kk)
          af[j][kk] = rdfrag(Ac, wrow + (mq * 4 + j) * 16 + lr, kk);
#pragma unroll
      for (int j = 0; j < 2; ++j)
#pragma unroll
        for (int kk = 0; kk < 2; ++kk)
          bf[j][kk] = rdfrag(Bc, wcol + (nq * 2 + j) * 16 + lr, kk);
      if (pf) {
        if (q == 0) {
          stage_half(A, brow, knx, An);
          stage_half(A, brow + 128, knx, An + 8192);
          if (BN == 128) stage_half(Bt, bcol, knx, Bn);
        }
        if (BN == 256 && q == 1) stage_half(Bt, bcol, knx, Bn);
        if (BN == 256 && q == 2) stage_half(Bt, bcol + 128, knx, Bn + 8192);
      }
      __builtin_amdgcn_s_barrier();
      __builtin_amdgcn_s_setprio(1);
#pragma unroll
      for (int j = 0; j < 4; ++j)
#pragma unroll
        for (int j2 = 0; j2 < 2; ++j2)
#pragma unroll
          for (int kk = 0; kk < 2; ++kk)
            acc[mq * 4 + j][nq * 2 + j2] = __builtin_amdgcn_mfma_f32_16x16x32_bf16(
                af[j][kk], bf[j2][kk], acc[mq * 4 + j][nq * 2 + j2], 0, 0, 0);
      __builtin_amdgcn_s_setprio(0);
      if (q == NPH - 1) {
        asm volatile("s_waitcnt vmcnt(0)" ::: "memory");
        __builtin_amdgcn_s_barrier();
        __builtin_amdgcn_sched_barrier(0);
      } else {
        __builtin_amdgcn_s_barrier();
      }
    }
  }

#pragma unroll
  for (int m = 0; m < MREP; ++m) {
#pragma unroll
    for (int n = 0; n < 4; ++n) {
#pragma unroll
      for (int qi = 0; qi < 4; ++qi) {
        int r = brow + wrow + m * 16 + g * 4 + qi;
        int c = bcol + wcol + n * 16 + lr;
        float v = acc[m][n][qi];
        if (MODE == MODE_QKV) {
          int which = c >> 10;
          int hd = c & 1023;
          const float* bp = which == 0 ? bias0 : (which == 1 ? bias1 : bias2);
          v += bp[hd];
          if (which == 0) v *= 0.1803368801f;  // 1/sqrt(dk) * log2(e)
          uint16_t* dst = which == 0 ? ob0 : (which == 1 ? ob1 : ob2);
          int b = r >> 11, tt = r & 2047;
          int h = hd >> 6, d = hd & 63;
          dst[((size_t)((b * NH + h) * SEQ + tt)) * DKH + d] = f2b(v);
        } else if (MODE == MODE_RELU) {
          v += bias0[c];
          v = fmaxf(v, 0.0f);
          ob0[(size_t)r * N + c] = f2b(v);
        } else {
          of[(size_t)r * N + c] = v;
        }
      }
    }
  }
}

// ---------------- attention (R8 version): 32 q/wave, grid 1024, XCD-local --------------
__global__ __launch_bounds__(256) void k_attn(const uint16_t* __restrict__ Qb,
                                              const uint16_t* __restrict__ Kb,
                                              const uint16_t* __restrict__ Vtg,
                                              uint16_t* __restrict__ ctx) {
  __shared__ __align__(16) uint16_t Ks[2][64 * 64];
  __shared__ __align__(16) uint16_t Vs[2][64 * 64];
  __shared__ float l_arr[4][32];
  const int o = blockIdx.x;
  const int wg = (o & 7) * 128 + (o >> 3);
  const int qt = wg & 15;
  const int bh = wg >> 4;
  const int b = bh >> 4, h = bh & 15;
  const uint16_t* Qp = Qb + (size_t)bh * SEQ * DKH;
  const uint16_t* Kp = Kb + (size_t)bh * SEQ * DKH;
  const uint16_t* Vp = Vtg + (size_t)bh * SEQ * DKH;  // [64][2048]
  const int t = threadIdx.x, w = t >> 6, l = t & 63;
  const int lo5 = l & 31, hh = l >> 5;
  const int qbase = qt * 128 + w * 32;

  short8 qf[4];
#pragma unroll
  for (int kc = 0; kc < 4; ++kc)
    qf[kc] = *reinterpret_cast<const short8*>(Qp + (size_t)(qbase + lo5) * DKH + kc * 16 + hh * 8);

  f32x16 oacc[2] = {};
  float lsum = 0.f;

  const int swz = ((l & 7) ^ ((l >> 3) & 7)) << 3;
  const int ci0 = w * 2, ci1 = w * 2 + 1;
  const int r0 = ci0 * 8 + (l >> 3), r1 = ci1 * 8 + (l >> 3);
  uint16_t* ldsK0 = &Ks[0][0] + ci0 * 512 + l * 8;
  uint16_t* ldsK1 = &Ks[0][0] + ci1 * 512 + l * 8;
  uint16_t* ldsV0 = &Vs[0][0] + ci0 * 512 + l * 8;
  uint16_t* ldsV1 = &Vs[0][0] + ci1 * 512 + l * 8;
  const uint16_t* gK0 = Kp + (size_t)r0 * DKH + swz;
  const uint16_t* gK1 = Kp + (size_t)r1 * DKH + swz;
  const uint16_t* gV0 = Vp + (size_t)r0 * SEQ + swz;
  const uint16_t* gV1 = Vp + (size_t)r1 * SEQ + swz;

  gload16(gK0, ldsK0);
  gload16(gK1, ldsK1);
  gload16(gV0, ldsV0);
  gload16(gV1, ldsV1);
  __syncthreads();

  for (int tile = 0; tile < 32; ++tile) {
    const int cur = tile & 1;
    if (tile < 31) {
      const int nxt = (cur ^ 1) * 4096;
      const size_t s0n = (size_t)(tile + 1) * 64;
      gload16(gK0 + s0n * DKH, ldsK0 + nxt);
      gload16(gK1 + s0n * DKH, ldsK1 + nxt);
      gload16(gV0 + s0n, ldsV0 + nxt);
      gload16(gV1 + s0n, ldsV1 + nxt);
    }
    const char* Kbuf = reinterpret_cast<const char*>(&Ks[cur][0]);
    const char* Vbuf = reinterpret_cast<const char*>(&Vs[cur][0]);

#pragma unroll
    for (int sblk = 0; sblk < 2; ++sblk) {
      short8 kf[4];
      const int krow = sblk * 32 + lo5;
      const int kxor = (krow & 7) << 4;
#pragma unroll
      for (int kc = 0; kc < 4; ++kc) {
        int cb = (kc * 32 + hh * 16) ^ kxor;
        kf[kc] = *reinterpret_cast<const short8*>(Kbuf + krow * 128 + cb);
      }
      short8 vf[2][2];
#pragma unroll
      for (int scl = 0; scl < 2; ++scl)
#pragma unroll
        for (int dblk = 0; dblk < 2; ++dblk) {
          int vrow = dblk * 32 + lo5;
          int cb = (sblk * 64 + scl * 32 + hh * 16) ^ ((vrow & 7) << 4);
          vf[scl][dblk] = *reinterpret_cast<const short8*>(Vbuf + vrow * 128 + cb);
        }

      f32x16 sa = {};
      __builtin_amdgcn_s_setprio(1);
#pragma unroll
      for (int kc = 0; kc < 4; ++kc)
        sa = __builtin_amdgcn_mfma_f32_32x32x16_bf16(kf[kc], qf[kc], sa, 0, 0, 0);
      __builtin_amdgcn_s_setprio(0);

      float p[16];
      float ls = 0.f;
#pragma unroll
      for (int r = 0; r < 16; ++r) {
        p[r] = __builtin_amdgcn_exp2f(sa[r]);
        ls += p[r];
      }
      lsum += ls;

      uint32_t clo[4], chi[4];
#pragma unroll
      for (int m = 0; m < 4; ++m) {
        asm("v_cvt_pk_bf16_f32 %0, %1, %2" : "=v"(clo[m]) : "v"(p[4 * m]), "v"(p[4 * m + 1]));
        asm("v_cvt_pk_bf16_f32 %0, %1, %2" : "=v"(chi[m]) : "v"(p[4 * m + 2]), "v"(p[4 * m + 3]));
      }

#pragma unroll
      for (int scl = 0; scl < 2; ++scl) {
        uint32_t a0 = clo[2 * scl], b0 = clo[2 * scl + 1];
        uint32_t a1 = chi[2 * scl], b1 = chi[2 * scl + 1];
        asm("v_permlane32_swap_b32 %0, %1" : "+v"(a0), "+v"(b0));
        asm("v_permlane32_swap_b32 %0, %1" : "+v"(a1), "+v"(b1));
        union {
          uint32_t u[4];
          short8 s;
        } pu;
        pu.u[0] = a0;
        pu.u[1] = a1;
        pu.u[2] = b0;
        pu.u[3] = b1;
        __builtin_amdgcn_s_setprio(1);
#pragma unroll
        for (int dblk = 0; dblk < 2; ++dblk)
          oacc[dblk] = __builtin_amdgcn_mfma_f32_32x32x16_bf16(pu.s, vf[scl][dblk], oacc[dblk], 0, 0, 0);
        __builtin_amdgcn_s_setprio(0);
      }
    }
    __syncthreads();
  }

  {
    float full = lsum + __shfl_xor(lsum, 32, 64);
    if (l < 32) l_arr[w][lo5] = full;
  }
#pragma unroll
  for (int r = 0; r < 16; ++r) {
    int q = (r & 3) + 8 * (r >> 2) + 4 * hh;
    float li = 1.0f / l_arr[w][q];
    int rowg = b * SEQ + qbase + q;
#pragma unroll
    for (int dblk = 0; dblk < 2; ++dblk) {
      int colg = h * DKH + dblk * 32 + lo5;
      ctx[(size_t)rowg * DMODEL + colg] = f2b(oacc[dblk][r] * li);
    }
  }
}

// ---------------- LayerNorm over (in + bias + res); res f32 or bf16 ----------------
template <bool WRITE_B, bool RESBF>
__global__ __launch_bounds__(256) void k_ln(const float* __restrict__ in,
                                            const float* __restrict__ bias,
                                            const void* __restrict__ res,
                                            const float* __restrict__ gam,
                                            const float* __restrict__ bet,
                                            float* __restrict__ outf,
                                            uint16_t* __restrict__ outb) {
  const int row = blockIdx.x;
  const int t = threadIdx.x, lane = t & 63, w = t >> 6;
  float4 v = reinterpret_cast<const float4*>(in + (size_t)row * DMODEL)[t];
  float4 bb0 = reinterpret_cast<const float4*>(bias)[t];
  float4 rr;
  if (RESBF) {
    uint2 ru = reinterpret_cast<const uint2*>((const uint16_t*)res + (size_t)row * DMODEL)[t];
    const uint16_t* rp = reinterpret_cast<const uint16_t*>(&ru);
    rr.x = b2f(rp[0]);
    rr.y = b2f(rp[1]);
    rr.z = b2f(rp[2]);
    rr.w = b2f(rp[3]);
  } else {
    rr = reinterpret_cast<const float4*>((const float*)res + (size_t)row * DMODEL)[t];
  }
  v.x += bb0.x + rr.x;
  v.y += bb0.y + rr.y;
  v.z += bb0.z + rr.z;
  v.w += bb0.w + rr.w;
  float s = v.x + v.y + v.z + v.w;
  float s2 = v.x * v.x + v.y * v.y + v.z * v.z + v.w * v.w;
#pragma unroll
  for (int off = 1; off < 64; off <<= 1) {
    s += __shfl_xor(s, off, 64);
    s2 += __shfl_xor(s2, off, 64);
  }
  __shared__ float rs[4], rq[4];
  if (lane == 0) {
    rs[w] = s;
    rq[w] = s2;
  }
  __syncthreads();
  float ts = rs[0] + rs[1] + rs[2] + rs[3];
  float tq = rq[0] + rq[1] + rq[2] + rq[3];
  const float inv = 1.0f / DMODEL;
  float mu = ts * inv;
  float var = tq * inv - mu * mu;
  float rstd = rsqrtf(var + 1e-5f);
  float4 gg = reinterpret_cast<const float4*>(gam)[t];
  float4 bb = reinterpret_cast<const float4*>(bet)[t];
  float4 y;
  y.x = (v.x - mu) * rstd * gg.x + bb.x;
  y.y = (v.y - mu) * rstd * gg.y + bb.y;
  y.z = (v.z - mu) * rstd * gg.z + bb.z;
  y.w = (v.w - mu) * rstd * gg.w + bb.w;
  if (WRITE_B) {
    uint16_t oo[4] = {f2b(y.x), f2b(y.y), f2b(y.z), f2b(y.w)};
    reinterpret_cast<uint2*>(outb)[(size_t)row * 256 + t] = *reinterpret_cast<uint2*>(oo);
  } else {
    reinterpret_cast<float4*>(outf)[(size_t)row * 256 + t] = y;
  }
}

extern "C" void kernel_launch(void* const* d_in, const int* in_sizes, int n_in, void* d_out,
                              int out_size, void* d_ws, size_t ws_size, hipStream_t stream) {
  const float* x = (const float*)d_in[0];
  const float* Wq = (const float*)d_in[1];
  const float* bq = (const float*)d_in[2];
  const float* Wk = (const float*)d_in[3];
  const float* bk = (const float*)d_in[4];
  const float* Wv = (const float*)d_in[5];
  const float* bv = (const float*)d_in[6];
  const float* Wo = (const float*)d_in[7];
  const float* bo = (const float*)d_in[8];
  const float* g1 = (const float*)d_in[9];
  const float* be1 = (const float*)d_in[10];
  const float* W1 = (const float*)d_in[11];
  const float* b1 = (const float*)d_in[12];
  const float* W2 = (const float*)d_in[13];
  const float* b2 = (const float*)d_in[14];
  const float* g2 = (const float*)d_in[15];
  const float* be2 = (const float*)d_in[16];

  char* ws = (char*)d_ws;
  size_t off = 0;
  auto alloc = [&](size_t bytes) {
    char* p = ws + off;
    off += (bytes + 255) & ~(size_t)255;
    return p;
  };
  uint16_t* wt_qkv = (uint16_t*)alloc(3072ull * 1024 * 2);
  uint16_t* wt_o = (uint16_t*)alloc(1024ull * 1024 * 2);
  uint16_t* wt_1 = (uint16_t*)alloc(4096ull * 1024 * 2);
  uint16_t* wt_2 = (uint16_t*)alloc(1024ull * 4096 * 2);
  uint16_t* xb = (uint16_t*)alloc(8192ull * 1024 * 2);  // x bf16; later aliased as ctx
  float* sum1 = (float*)alloc(8192ull * 1024 * 4);      // raw GEMM f32 out (Wo, then FFN2)
  uint16_t* vt = (uint16_t*)alloc(8192ull * 1024 * 2);  // V^T
  char* big = alloc(16777216ull + 67108864ull);         // QKV (48MB) -> x1b(16MB)+h(64MB)
  uint16_t* Qbuf = (uint16_t*)big;
  uint16_t* Kbuf = (uint16_t*)(big + 16777216ull);
  uint16_t* Vbuf = (uint16_t*)(big + 2 * 16777216ull);
  uint16_t* ctx = xb;
  uint16_t* x1b = (uint16_t*)big;                   // alias: Q dead after attention
  uint16_t* hbuf = (uint16_t*)(big + 16777216ull);  // alias: K,V dead after attention
  (void)ws_size;

  // 1. all weight prep in one launch
  k_tcast_all<<<12288, 256, 0, stream>>>(Wq, Wk, Wv, Wo, W1, W2, wt_qkv, wt_o, wt_1, wt_2);
  // 2. cast x
  k_castx<<<8192, 256, 0, stream>>>(x, xb);
  // 3. QKV projection, BN=128 -> 768 blocks (3 full dispatch waves)
  k_gemm2<128, MODE_QKV><<<768, 512, 0, stream>>>(
      xb, wt_qkv, 8192, 3072, 1024, 24, bq, bk, bv, Qbuf, Kbuf, Vbuf, nullptr);
  // 3.5 V transpose
  k_vtrans<<<dim3(32, 64), 256, 0, stream>>>(Vbuf, vt);
  // 4. attention -> ctx (32 q/wave, 1024 blocks, XCD-local)
  k_attn<<<1024, 256, 0, stream>>>(Qbuf, Kbuf, vt, ctx);
  // 5. Wo projection raw -> sum1
  k_gemm2<128, MODE_RAW><<<256, 512, 0, stream>>>(
      ctx, wt_o, 8192, 1024, 1024, 8, nullptr, nullptr, nullptr, nullptr, nullptr, nullptr, sum1);
  // 6. LN1(sum1 + bo + x) -> x1b (bf16 only)
  k_ln<true, false><<<8192, 256, 0, stream>>>(sum1, bo, x, g1, be1, nullptr, x1b);
  // 7. FFN1: relu(x1 @ W1 + b1) -> h bf16
  k_gemm2<256, MODE_RELU><<<512, 512, 0, stream>>>(
      x1b, wt_1, 8192, 4096, 1024, 16, b1, nullptr, nullptr, hbuf, nullptr, nullptr, nullptr);
  // 8. FFN2 raw -> sum1
  k_gemm2<128, MODE_RAW><<<256, 512, 0, stream>>>(
      hbuf, wt_2, 8192, 1024, 4096, 8, nullptr, nullptr, nullptr, nullptr, nullptr, nullptr, sum1);
  // 9. LN2(sum1 + b2 + x1b[bf16]) -> output (f32)
  k_ln<false, true><<<8192, 256, 0, stream>>>(sum1, b2, x1b, g2, be2, (float*)d_out, nullptr);
}

// Round 11
// 399.012 us; speedup vs baseline: 1.0567x; 1.0073x over previous
//
#include <hip/hip_runtime.h>
#include <hip/hip_bf16.h>
#include <stdint.h>

typedef __attribute__((ext_vector_type(8))) short short8;
typedef __attribute__((ext_vector_type(4))) float f32x4;
typedef __attribute__((ext_vector_type(16))) float f32x16;

#define SEQ 2048
#define DMODEL 1024
#define NH 16
#define DKH 64

__device__ __forceinline__ uint16_t f2b(float f) {
  uint32_t u = __float_as_uint(f);
  uint32_t r = (u + 0x7fff + ((u >> 16) & 1)) >> 16;
  return (uint16_t)r;
}
__device__ __forceinline__ float b2f(uint16_t u) {
  return __uint_as_float(((uint32_t)u) << 16);
}

__device__ __forceinline__ void gload16(const uint16_t* g, uint16_t* l) {
  __builtin_amdgcn_global_load_lds((const __attribute__((address_space(1))) void*)g,
                                   (__attribute__((address_space(3))) void*)l, 16, 0, 0);
}

// ---------------- all weight cast+transposes AND x-cast in ONE kernel ----------------
__global__ __launch_bounds__(256) void k_prep(
    const float* __restrict__ Wq, const float* __restrict__ Wk, const float* __restrict__ Wv,
    const float* __restrict__ Wo, const float* __restrict__ W1, const float* __restrict__ W2,
    const float* __restrict__ x, uint16_t* __restrict__ wt_qkv, uint16_t* __restrict__ wt_o,
    uint16_t* __restrict__ wt_1, uint16_t* __restrict__ wt_2, uint16_t* __restrict__ xb) {
  const int id = blockIdx.x;
  if (id >= 12288) {  // castx part: 8192 blocks, 1024 elems each
    int i = (id - 12288) * 256 + threadIdx.x;
    float4 v = reinterpret_cast<const float4*>(x)[i];
    uint16_t o[4] = {f2b(v.x), f2b(v.y), f2b(v.z), f2b(v.w)};
    reinterpret_cast<uint2*>(xb)[i] = *reinterpret_cast<uint2*>(o);
    return;
  }
  __shared__ float tile[32][33];
  const float* W;
  uint16_t* Wt;
  int K, N, bx, by;
  if (id < 4096) {
    int wsel = id >> 10, r = id & 1023;
    K = 1024; N = 1024; bx = r & 31; by = r >> 5;
    W = wsel == 0 ? Wq : (wsel == 1 ? Wk : (wsel == 2 ? Wv : Wo));
    Wt = wsel == 3 ? wt_o : wt_qkv + wsel * 1024 * 1024;
  } else if (id < 8192) {
    int r = id - 4096;
    K = 1024; N = 4096; bx = r & 127; by = r >> 7;
    W = W1; Wt = wt_1;
  } else {
    int r = id - 8192;
    K = 4096; N = 1024; bx = r & 31; by = r >> 5;
    W = W2; Wt = wt_2;
  }
  const int n0 = bx * 32, k0 = by * 32;
  const int tx = threadIdx.x & 31, ty = threadIdx.x >> 5;
#pragma unroll
  for (int i = 0; i < 32; i += 8)
    tile[ty + i][tx] = W[(size_t)(k0 + ty + i) * N + n0 + tx];
  __syncthreads();
#pragma unroll
  for (int i = 0; i < 32; i += 8)
    Wt[(size_t)(n0 + ty + i) * K + k0 + tx] = f2b(tile[tx][ty + i]);
}

// ---------------- V transpose per (b,h): [2048][64] -> [64][2048] bf16 ----------------
__global__ __launch_bounds__(256) void k_vtrans(const uint16_t* __restrict__ V,
                                                uint16_t* __restrict__ Vt) {
  __shared__ uint16_t tile[64][72];
  const int s0 = blockIdx.x * 64;
  const uint16_t* Vp = V + (size_t)blockIdx.y * SEQ * DKH;
  uint16_t* Vtp = Vt + (size_t)blockIdx.y * SEQ * DKH;
  const int t = threadIdx.x;
#pragma unroll
  for (int i = t; i < 512; i += 256) {
    int r = i >> 3, c8 = (i & 7) << 3;
    *reinterpret_cast<uint4*>(&tile[r][c8]) =
        *reinterpret_cast<const uint4*>(Vp + (size_t)(s0 + r) * DKH + c8);
  }
  __syncthreads();
#pragma unroll
  for (int i = t; i < 512; i += 256) {
    int d = i >> 3, s8 = (i & 7) << 3;
    uint16_t tmp[8];
#pragma unroll
    for (int j = 0; j < 8; ++j) tmp[j] = tile[s8 + j][d];
    *reinterpret_cast<uint4*>(Vtp + (size_t)d * SEQ + s0 + s8) = *reinterpret_cast<uint4*>(tmp);
  }
}

// ---------------- GEMM v2 (R6 schedule + early stage issue): 256-row tile, BK=64 -------
#define MODE_QKV 0
#define MODE_RAW 1
#define MODE_RELU 2

template <int BN, int MODE>
__global__ __launch_bounds__(512, 2) void k_gemm2(
    const uint16_t* __restrict__ A, const uint16_t* __restrict__ Bt, int M, int N, int K,
    int nx, const float* __restrict__ bias0, const float* __restrict__ bias1,
    const float* __restrict__ bias2, uint16_t* __restrict__ ob0, uint16_t* __restrict__ ob1,
    uint16_t* __restrict__ ob2, float* __restrict__ of) {
  constexpr int ASZ = 256 * 64;
  constexpr int BSZ = BN * 64;
  __shared__ __align__(16) uint16_t lds[2 * (ASZ + BSZ)];
  uint16_t* const Abase = lds;
  uint16_t* const Bbase = lds + 2 * ASZ;
  constexpr int WN = (BN == 256) ? 4 : 2;
  constexpr int MREP = (BN == 256) ? 8 : 4;
  constexpr int NPH = (BN == 256) ? 4 : 2;
  const int o = blockIdx.x;
  const int chunk = gridDim.x >> 3;
  const int wg = (o & 7) * chunk + (o >> 3);
  const int brow = (wg / nx) << 8;
  const int bcol = (wg % nx) * BN;
  const int t = threadIdx.x;
  const int wid = t >> 6, l = t & 63, g = l >> 4, lr = l & 15;
  const int wr = wid / WN, wc = wid % WN;
  const int wrow = wr * (MREP * 16);
  const int wcol = wc * 64;

  const int srow = t >> 3;
  const int ss0 = (t & 7) ^ (srow & 7);
  const int ss1 = (t & 7) ^ ((srow + 64) & 7);

  auto stage_half = [&](const uint16_t* gsrc, int grow0, int kk, uint16_t* ldst) {
    gload16(gsrc + (size_t)(grow0 + srow) * K + kk + ss0 * 8, ldst + t * 8);
    gload16(gsrc + (size_t)(grow0 + srow + 64) * K + kk + ss1 * 8, ldst + 4096 + t * 8);
  };
  auto rdfrag = [&](const uint16_t* buf, int ar, int kk) -> short8 {
    int slot = ((kk << 2) + g) ^ (ar & 7);
    return *reinterpret_cast<const short8*>(buf + ar * 64 + slot * 8);
  };

  f32x4 acc[MREP][4] = {};
  const int nt = K >> 6;

  stage_half(A, brow, 0, Abase);
  stage_half(A, brow + 128, 0, Abase + 8192);
  stage_half(Bt, bcol, 0, Bbase);
  if (BN == 256) stage_half(Bt, bcol + 128, 0, Bbase + 8192);
  __syncthreads();

  for (int kt = 0; kt < nt; ++kt) {
    const int cur = kt & 1;
    const uint16_t* Ac = Abase + cur * ASZ;
    const uint16_t* Bc = Bbase + cur * BSZ;
    uint16_t* An = Abase + (cur ^ 1) * ASZ;
    uint16_t* Bn = Bbase + (cur ^ 1) * BSZ;
    const bool pf = (kt + 1 < nt);
    const int knx = (kt + 1) << 6;
#pragma unroll
    for (int q = 0; q < NPH; ++q) {
      const int mq = (BN == 256) ? (q >> 1) : 0;
      const int nq = (BN == 256) ? (q & 1) : q;
      short8 af[4][2], bf[2][2];
#pragma unroll
      for (int j = 0; j < 4; ++j)
#pragma unroll
        for (int kk = 0; kk < 2; ++kk)
          af[j][kk] = rdfrag(Ac, wrow + (mq * 4 + j) * 16 + lr, kk);
#pragma unroll
      for (int j = 0; j < 2; ++j)
#pragma unroll
        for (int kk = 0; kk < 2; ++kk)
          bf[j][kk] = rdfrag(Bc, wcol + (nq * 2 + j) * 16 + lr, kk);
      if (pf && q == 0) {  // issue ALL staging at phase 0: max issue-to-wait distance
        stage_half(A, brow, knx, An);
        stage_half(A, brow + 128, knx, An + 8192);
        stage_half(Bt, bcol, knx, Bn);
        if (BN == 256) stage_half(Bt, bcol + 128, knx, Bn + 8192);
      }
      __builtin_amdgcn_s_barrier();
      __builtin_amdgcn_s_setprio(1);
#pragma unroll
      for (int j = 0; j < 4; ++j)
#pragma unroll
        for (int j2 = 0; j2 < 2; ++j2)
#pragma unroll
          for (int kk = 0; kk < 2; ++kk)
            acc[mq * 4 + j][nq * 2 + j2] = __builtin_amdgcn_mfma_f32_16x16x32_bf16(
                af[j][kk], bf[j2][kk], acc[mq * 4 + j][nq * 2 + j2], 0, 0, 0);
      __builtin_amdgcn_s_setprio(0);
      if (q == NPH - 1) {
        asm volatile("s_waitcnt vmcnt(0)" ::: "memory");
        __builtin_amdgcn_s_barrier();
        __builtin_amdgcn_sched_barrier(0);
      } else {
        __builtin_amdgcn_s_barrier();
      }
    }
  }

#pragma unroll
  for (int m = 0; m < MREP; ++m) {
#pragma unroll
    for (int n = 0; n < 4; ++n) {
#pragma unroll
      for (int qi = 0; qi < 4; ++qi) {
        int r = brow + wrow + m * 16 + g * 4 + qi;
        int c = bcol + wcol + n * 16 + lr;
        float v = acc[m][n][qi];
        if (MODE == MODE_QKV) {
          int which = c >> 10;
          int hd = c & 1023;
          const float* bp = which == 0 ? bias0 : (which == 1 ? bias1 : bias2);
          v += bp[hd];
          if (which == 0) v *= 0.1803368801f;  // 1/sqrt(dk) * log2(e)
          uint16_t* dst = which == 0 ? ob0 : (which == 1 ? ob1 : ob2);
          int b = r >> 11, tt = r & 2047;
          int h = hd >> 6, d = hd & 63;
          dst[((size_t)((b * NH + h) * SEQ + tt)) * DKH + d] = f2b(v);
        } else if (MODE == MODE_RELU) {
          v += bias0[c];
          v = fmaxf(v, 0.0f);
          ob0[(size_t)r * N + c] = f2b(v);
        } else {
          of[(size_t)r * N + c] = v;
        }
      }
    }
  }
}

// ---------------- attention v7: sblk-pipelined (both QK^T issued before softmax) -------
__global__ __launch_bounds__(256) void k_attn(const uint16_t* __restrict__ Qb,
                                              const uint16_t* __restrict__ Kb,
                                              const uint16_t* __restrict__ Vtg,
                                              uint16_t* __restrict__ ctx) {
  __shared__ __align__(16) uint16_t Ks[2][64 * 64];
  __shared__ __align__(16) uint16_t Vs[2][64 * 64];
  __shared__ float l_arr[4][32];
  const int o = blockIdx.x;
  const int wg = (o & 7) * 128 + (o >> 3);
  const int qt = wg & 15;
  const int bh = wg >> 4;
  const int b = bh >> 4, h = bh & 15;
  const uint16_t* Qp = Qb + (size_t)bh * SEQ * DKH;
  const uint16_t* Kp = Kb + (size_t)bh * SEQ * DKH;
  const uint16_t* Vp = Vtg + (size_t)bh * SEQ * DKH;  // [64][2048]
  const int t = threadIdx.x, w = t >> 6, l = t & 63;
  const int lo5 = l & 31, hh = l >> 5;
  const int qbase = qt * 128 + w * 32;

  short8 qf[4];
#pragma unroll
  for (int kc = 0; kc < 4; ++kc)
    qf[kc] = *reinterpret_cast<const short8*>(Qp + (size_t)(qbase + lo5) * DKH + kc * 16 + hh * 8);

  f32x16 oacc[2] = {};
  float lsum = 0.f;

  const int swz = ((l & 7) ^ ((l >> 3) & 7)) << 3;
  const int ci0 = w * 2, ci1 = w * 2 + 1;
  const int r0 = ci0 * 8 + (l >> 3), r1 = ci1 * 8 + (l >> 3);
  uint16_t* ldsK0 = &Ks[0][0] + ci0 * 512 + l * 8;
  uint16_t* ldsK1 = &Ks[0][0] + ci1 * 512 + l * 8;
  uint16_t* ldsV0 = &Vs[0][0] + ci0 * 512 + l * 8;
  uint16_t* ldsV1 = &Vs[0][0] + ci1 * 512 + l * 8;
  const uint16_t* gK0 = Kp + (size_t)r0 * DKH + swz;
  const uint16_t* gK1 = Kp + (size_t)r1 * DKH + swz;
  const uint16_t* gV0 = Vp + (size_t)r0 * SEQ + swz;
  const uint16_t* gV1 = Vp + (size_t)r1 * SEQ + swz;

  gload16(gK0, ldsK0);
  gload16(gK1, ldsK1);
  gload16(gV0, ldsV0);
  gload16(gV1, ldsV1);
  __syncthreads();

  for (int tile = 0; tile < 32; ++tile) {
    const int cur = tile & 1;
    if (tile < 31) {
      const int nxt = (cur ^ 1) * 4096;
      const size_t s0n = (size_t)(tile + 1) * 64;
      gload16(gK0 + s0n * DKH, ldsK0 + nxt);
      gload16(gK1 + s0n * DKH, ldsK1 + nxt);
      gload16(gV0 + s0n, ldsV0 + nxt);
      gload16(gV1 + s0n, ldsV1 + nxt);
    }
    const char* Kbuf = reinterpret_cast<const char*>(&Ks[cur][0]);
    const char* Vbuf = reinterpret_cast<const char*>(&Vs[cur][0]);

    // --- issue BOTH QK^T clusters before any softmax (MFMA ∥ VALU overlap) ---
    short8 kf[2][4];
#pragma unroll
    for (int sblk = 0; sblk < 2; ++sblk) {
      const int krow = sblk * 32 + lo5;
      const int kxor = (krow & 7) << 4;
#pragma unroll
      for (int kc = 0; kc < 4; ++kc) {
        int cb = (kc * 32 + hh * 16) ^ kxor;
        kf[sblk][kc] = *reinterpret_cast<const short8*>(Kbuf + krow * 128 + cb);
      }
    }
    f32x16 sa[2];
#pragma unroll
    for (int sblk = 0; sblk < 2; ++sblk) {
      f32x16 z = {};
      __builtin_amdgcn_s_setprio(1);
#pragma unroll
      for (int kc = 0; kc < 4; ++kc)
        z = __builtin_amdgcn_mfma_f32_32x32x16_bf16(kf[sblk][kc], qf[kc], z, 0, 0, 0);
      __builtin_amdgcn_s_setprio(0);
      sa[sblk] = z;
    }

#pragma unroll
    for (int sblk = 0; sblk < 2; ++sblk) {
      short8 vf[2][2];
#pragma unroll
      for (int scl = 0; scl < 2; ++scl)
#pragma unroll
        for (int dblk = 0; dblk < 2; ++dblk) {
          int vrow = dblk * 32 + lo5;
          int cb = (sblk * 64 + scl * 32 + hh * 16) ^ ((vrow & 7) << 4);
          vf[scl][dblk] = *reinterpret_cast<const short8*>(Vbuf + vrow * 128 + cb);
        }

      float p[16];
      float ls = 0.f;
#pragma unroll
      for (int r = 0; r < 16; ++r) {
        p[r] = __builtin_amdgcn_exp2f(sa[sblk][r]);
        ls += p[r];
      }
      lsum += ls;

      uint32_t clo[4], chi[4];
#pragma unroll
      for (int m = 0; m < 4; ++m) {
        asm("v_cvt_pk_bf16_f32 %0, %1, %2" : "=v"(clo[m]) : "v"(p[4 * m]), "v"(p[4 * m + 1]));
        asm("v_cvt_pk_bf16_f32 %0, %1, %2" : "=v"(chi[m]) : "v"(p[4 * m + 2]), "v"(p[4 * m + 3]));
      }

#pragma unroll
      for (int scl = 0; scl < 2; ++scl) {
        uint32_t a0 = clo[2 * scl], b0 = clo[2 * scl + 1];
        uint32_t a1 = chi[2 * scl], b1 = chi[2 * scl + 1];
        asm("v_permlane32_swap_b32 %0, %1" : "+v"(a0), "+v"(b0));
        asm("v_permlane32_swap_b32 %0, %1" : "+v"(a1), "+v"(b1));
        union {
          uint32_t u[4];
          short8 s;
        } pu;
        pu.u[0] = a0;
        pu.u[1] = a1;
        pu.u[2] = b0;
        pu.u[3] = b1;
        __builtin_amdgcn_s_setprio(1);
#pragma unroll
        for (int dblk = 0; dblk < 2; ++dblk)
          oacc[dblk] = __builtin_amdgcn_mfma_f32_32x32x16_bf16(pu.s, vf[scl][dblk], oacc[dblk], 0, 0, 0);
        __builtin_amdgcn_s_setprio(0);
      }
    }
    __syncthreads();
  }

  {
    float full = lsum + __shfl_xor(lsum, 32, 64);
    if (l < 32) l_arr[w][lo5] = full;
  }
#pragma unroll
  for (int r = 0; r < 16; ++r) {
    int q = (r & 3) + 8 * (r >> 2) + 4 * hh;
    float li = 1.0f / l_arr[w][q];
    int rowg = b * SEQ + qbase + q;
#pragma unroll
    for (int dblk = 0; dblk < 2; ++dblk) {
      int colg = h * DKH + dblk * 32 + lo5;
      ctx[(size_t)rowg * DMODEL + colg] = f2b(oacc[dblk][r] * li);
    }
  }
}

// ---------------- LayerNorm over (in + bias + res); res f32 or bf16 ----------------
template <bool WRITE_B, bool RESBF>
__global__ __launch_bounds__(256) void k_ln(const float* __restrict__ in,
                                            const float* __restrict__ bias,
                                            const void* __restrict__ res,
                                            const float* __restrict__ gam,
                                            const float* __restrict__ bet,
                                            float* __restrict__ outf,
                                            uint16_t* __restrict__ outb) {
  const int row = blockIdx.x;
  const int t = threadIdx.x, lane = t & 63, w = t >> 6;
  float4 v = reinterpret_cast<const float4*>(in + (size_t)row * DMODEL)[t];
  float4 bb0 = reinterpret_cast<const float4*>(bias)[t];
  float4 rr;
  if (RESBF) {
    uint2 ru = reinterpret_cast<const uint2*>((const uint16_t*)res + (size_t)row * DMODEL)[t];
    const uint16_t* rp = reinterpret_cast<const uint16_t*>(&ru);
    rr.x = b2f(rp[0]);
    rr.y = b2f(rp[1]);
    rr.z = b2f(rp[2]);
    rr.w = b2f(rp[3]);
  } else {
    rr = reinterpret_cast<const float4*>((const float*)res + (size_t)row * DMODEL)[t];
  }
  v.x += bb0.x + rr.x;
  v.y += bb0.y + rr.y;
  v.z += bb0.z + rr.z;
  v.w += bb0.w + rr.w;
  float s = v.x + v.y + v.z + v.w;
  float s2 = v.x * v.x + v.y * v.y + v.z * v.z + v.w * v.w;
#pragma unroll
  for (int off = 1; off < 64; off <<= 1) {
    s += __shfl_xor(s, off, 64);
    s2 += __shfl_xor(s2, off, 64);
  }
  __shared__ float rs[4], rq[4];
  if (lane == 0) {
    rs[w] = s;
    rq[w] = s2;
  }
  __syncthreads();
  float ts = rs[0] + rs[1] + rs[2] + rs[3];
  float tq = rq[0] + rq[1] + rq[2] + rq[3];
  const float inv = 1.0f / DMODEL;
  float mu = ts * inv;
  float var = tq * inv - mu * mu;
  float rstd = rsqrtf(var + 1e-5f);
  float4 gg = reinterpret_cast<const float4*>(gam)[t];
  float4 bb = reinterpret_cast<const float4*>(bet)[t];
  float4 y;
  y.x = (v.x - mu) * rstd * gg.x + bb.x;
  y.y = (v.y - mu) * rstd * gg.y + bb.y;
  y.z = (v.z - mu) * rstd * gg.z + bb.z;
  y.w = (v.w - mu) * rstd * gg.w + bb.w;
  if (WRITE_B) {
    uint16_t oo[4] = {f2b(y.x), f2b(y.y), f2b(y.z), f2b(y.w)};
    reinterpret_cast<uint2*>(outb)[(size_t)row * 256 + t] = *reinterpret_cast<uint2*>(oo);
  } else {
    reinterpret_cast<float4*>(outf)[(size_t)row * 256 + t] = y;
  }
}

extern "C" void kernel_launch(void* const* d_in, const int* in_sizes, int n_in, void* d_out,
                              int out_size, void* d_ws, size_t ws_size, hipStream_t stream) {
  const float* x = (const float*)d_in[0];
  const float* Wq = (const float*)d_in[1];
  const float* bq = (const float*)d_in[2];
  const float* Wk = (const float*)d_in[3];
  const float* bk = (const float*)d_in[4];
  const float* Wv = (const float*)d_in[5];
  const float* bv = (const float*)d_in[6];
  const float* Wo = (const float*)d_in[7];
  const float* bo = (const float*)d_in[8];
  const float* g1 = (const float*)d_in[9];
  const float* be1 = (const float*)d_in[10];
  const float* W1 = (const float*)d_in[11];
  const float* b1 = (const float*)d_in[12];
  const float* W2 = (const float*)d_in[13];
  const float* b2 = (const float*)d_in[14];
  const float* g2 = (const float*)d_in[15];
  const float* be2 = (const float*)d_in[16];

  char* ws = (char*)d_ws;
  size_t off = 0;
  auto alloc = [&](size_t bytes) {
    char* p = ws + off;
    off += (bytes + 255) & ~(size_t)255;
    return p;
  };
  uint16_t* wt_qkv = (uint16_t*)alloc(3072ull * 1024 * 2);
  uint16_t* wt_o = (uint16_t*)alloc(1024ull * 1024 * 2);
  uint16_t* wt_1 = (uint16_t*)alloc(4096ull * 1024 * 2);
  uint16_t* wt_2 = (uint16_t*)alloc(1024ull * 4096 * 2);
  uint16_t* xb = (uint16_t*)alloc(8192ull * 1024 * 2);  // x bf16; later aliased as ctx
  float* sum1 = (float*)alloc(8192ull * 1024 * 4);      // raw GEMM f32 out (Wo, then FFN2)
  uint16_t* vt = (uint16_t*)alloc(8192ull * 1024 * 2);  // V^T
  char* big = alloc(16777216ull + 67108864ull);         // QKV (48MB) -> x1b(16MB)+h(64MB)
  uint16_t* Qbuf = (uint16_t*)big;
  uint16_t* Kbuf = (uint16_t*)(big + 16777216ull);
  uint16_t* Vbuf = (uint16_t*)(big + 2 * 16777216ull);
  uint16_t* ctx = xb;
  uint16_t* x1b = (uint16_t*)big;                   // alias: Q dead after attention
  uint16_t* hbuf = (uint16_t*)(big + 16777216ull);  // alias: K,V dead after attention
  (void)ws_size;

  // 1. all prep (weight transposes + x cast) in one launch
  k_prep<<<20480, 256, 0, stream>>>(Wq, Wk, Wv, Wo, W1, W2, x, wt_qkv, wt_o, wt_1, wt_2, xb);
  // 2. QKV projection, BN=128 -> 768 blocks (3 full dispatch waves)
  k_gemm2<128, MODE_QKV><<<768, 512, 0, stream>>>(
      xb, wt_qkv, 8192, 3072, 1024, 24, bq, bk, bv, Qbuf, Kbuf, Vbuf, nullptr);
  // 2.5 V transpose
  k_vtrans<<<dim3(32, 64), 256, 0, stream>>>(Vbuf, vt);
  // 3. attention -> ctx (32 q/wave, 1024 blocks, XCD-local, sblk-pipelined)
  k_attn<<<1024, 256, 0, stream>>>(Qbuf, Kbuf, vt, ctx);
  // 4. Wo projection raw -> sum1
  k_gemm2<128, MODE_RAW><<<256, 512, 0, stream>>>(
      ctx, wt_o, 8192, 1024, 1024, 8, nullptr, nullptr, nullptr, nullptr, nullptr, nullptr, sum1);
  // 5. LN1(sum1 + bo + x) -> x1b (bf16 only)
  k_ln<true, false><<<8192, 256, 0, stream>>>(sum1, bo, x, g1, be1, nullptr, x1b);
  // 6. FFN1: relu(x1 @ W1 + b1) -> h bf16
  k_gemm2<256, MODE_RELU><<<512, 512, 0, stream>>>(
      x1b, wt_1, 8192, 4096, 1024, 16, b1, nullptr, nullptr, hbuf, nullptr, nullptr, nullptr);
  // 7. FFN2 raw -> sum1
  k_gemm2<128, MODE_RAW><<<256, 512, 0, stream>>>(
      hbuf, wt_2, 8192, 1024, 4096, 8, nullptr, nullptr, nullptr, nullptr, nullptr, nullptr, sum1);
  // 8. LN2(sum1 + b2 + x1b[bf16]) -> output (f32)
  k_ln<false, true><<<8192, 256, 0, stream>>>(sum1, b2, x1b, g2, be2, (float*)d_out, nullptr);
}

// Round 13
// 389.332 us; speedup vs baseline: 1.0830x; 1.0249x over previous
//
#include <hip/hip_runtime.h>
#include <hip/hip_bf16.h>
#include <stdint.h>

typedef __attribute__((ext_vector_type(8))) short short8;
typedef __attribute__((ext_vector_type(4))) float f32x4;
typedef __attribute__((ext_vector_type(16))) float f32x16;

#define SEQ 2048
#define DMODEL 1024
#define NH 16
#define DKH 64

__device__ __forceinline__ uint16_t f2b(float f) {
  uint32_t u = __float_as_uint(f);
  uint32_t r = (u + 0x7fff + ((u >> 16) & 1)) >> 16;
  return (uint16_t)r;
}
__device__ __forceinline__ float b2f(uint16_t u) {
  return __uint_as_float(((uint32_t)u) << 16);
}

__device__ __forceinline__ void gload16(const uint16_t* g, uint16_t* l) {
  __builtin_amdgcn_global_load_lds((const __attribute__((address_space(1))) void*)g,
                                   (__attribute__((address_space(3))) void*)l, 16, 0, 0);
}

// ---------------- all weight cast+transposes AND x-cast in ONE kernel ----------------
__global__ __launch_bounds__(256) void k_prep(
    const float* __restrict__ Wq, const float* __restrict__ Wk, const float* __restrict__ Wv,
    const float* __restrict__ Wo, const float* __restrict__ W1, const float* __restrict__ W2,
    const float* __restrict__ x, uint16_t* __restrict__ wt_qkv, uint16_t* __restrict__ wt_o,
    uint16_t* __restrict__ wt_1, uint16_t* __restrict__ wt_2, uint16_t* __restrict__ xb) {
  const int id = blockIdx.x;
  if (id >= 12288) {  // castx part
    int i = (id - 12288) * 256 + threadIdx.x;
    float4 v = reinterpret_cast<const float4*>(x)[i];
    uint16_t o[4] = {f2b(v.x), f2b(v.y), f2b(v.z), f2b(v.w)};
    reinterpret_cast<uint2*>(xb)[i] = *reinterpret_cast<uint2*>(o);
    return;
  }
  __shared__ float tile[32][33];
  const float* W;
  uint16_t* Wt;
  int K, N, bx, by;
  if (id < 4096) {
    int wsel = id >> 10, r = id & 1023;
    K = 1024; N = 1024; bx = r & 31; by = r >> 5;
    W = wsel == 0 ? Wq : (wsel == 1 ? Wk : (wsel == 2 ? Wv : Wo));
    Wt = wsel == 3 ? wt_o : wt_qkv + wsel * 1024 * 1024;
  } else if (id < 8192) {
    int r = id - 4096;
    K = 1024; N = 4096; bx = r & 127; by = r >> 7;
    W = W1; Wt = wt_1;
  } else {
    int r = id - 8192;
    K = 4096; N = 1024; bx = r & 31; by = r >> 5;
    W = W2; Wt = wt_2;
  }
  const int n0 = bx * 32, k0 = by * 32;
  const int tx = threadIdx.x & 31, ty = threadIdx.x >> 5;
#pragma unroll
  for (int i = 0; i < 32; i += 8)
    tile[ty + i][tx] = W[(size_t)(k0 + ty + i) * N + n0 + tx];
  __syncthreads();
#pragma unroll
  for (int i = 0; i < 32; i += 8)
    Wt[(size_t)(n0 + ty + i) * K + k0 + tx] = f2b(tile[tx][ty + i]);
}

// ---------------- GEMM (R6 schedule + early stage issue); V-transpose fused epilogue ---
#define MODE_QKV 0
#define MODE_RAWB 1
#define MODE_RELU 2

template <int BN, int MODE>
__global__ __launch_bounds__(512, 2) void k_gemm2(
    const uint16_t* __restrict__ A, const uint16_t* __restrict__ Bt, int M, int N, int K,
    int nx, const float* __restrict__ bias0, const float* __restrict__ bias1,
    const float* __restrict__ bias2, uint16_t* __restrict__ ob0, uint16_t* __restrict__ ob1,
    uint16_t* __restrict__ ob2, float* __restrict__ of) {
  constexpr int ASZ = 256 * 64;
  constexpr int BSZ = BN * 64;
  __shared__ __align__(16) uint16_t lds[2 * (ASZ + BSZ)];
  uint16_t* const Abase = lds;
  uint16_t* const Bbase = lds + 2 * ASZ;
  constexpr int WN = (BN == 256) ? 4 : 2;
  constexpr int MREP = (BN == 256) ? 8 : 4;
  constexpr int NPH = (BN == 256) ? 4 : 2;
  const int o = blockIdx.x;
  const int chunk = gridDim.x >> 3;
  const int wg = (o & 7) * chunk + (o >> 3);
  const int brow = (wg / nx) << 8;
  const int bcol = (wg % nx) * BN;
  const int t = threadIdx.x;
  const int wid = t >> 6, l = t & 63, g = l >> 4, lr = l & 15;
  const int wr = wid / WN, wc = wid % WN;
  const int wrow = wr * (MREP * 16);
  const int wcol = wc * 64;

  const int srow = t >> 3;
  const int ss0 = (t & 7) ^ (srow & 7);
  const int ss1 = (t & 7) ^ ((srow + 64) & 7);

  auto stage_half = [&](const uint16_t* gsrc, int grow0, int kk, uint16_t* ldst) {
    gload16(gsrc + (size_t)(grow0 + srow) * K + kk + ss0 * 8, ldst + t * 8);
    gload16(gsrc + (size_t)(grow0 + srow + 64) * K + kk + ss1 * 8, ldst + 4096 + t * 8);
  };
  auto rdfrag = [&](const uint16_t* buf, int ar, int kk) -> short8 {
    int slot = ((kk << 2) + g) ^ (ar & 7);
    return *reinterpret_cast<const short8*>(buf + ar * 64 + slot * 8);
  };

  f32x4 acc[MREP][4] = {};
  const int nt = K >> 6;

  stage_half(A, brow, 0, Abase);
  stage_half(A, brow + 128, 0, Abase + 8192);
  stage_half(Bt, bcol, 0, Bbase);
  if (BN == 256) stage_half(Bt, bcol + 128, 0, Bbase + 8192);
  __syncthreads();

  for (int kt = 0; kt < nt; ++kt) {
    const int cur = kt & 1;
    const uint16_t* Ac = Abase + cur * ASZ;
    const uint16_t* Bc = Bbase + cur * BSZ;
    uint16_t* An = Abase + (cur ^ 1) * ASZ;
    uint16_t* Bn = Bbase + (cur ^ 1) * BSZ;
    const bool pf = (kt + 1 < nt);
    const int knx = (kt + 1) << 6;
#pragma unroll
    for (int q = 0; q < NPH; ++q) {
      const int mq = (BN == 256) ? (q >> 1) : 0;
      const int nq = (BN == 256) ? (q & 1) : q;
      short8 af[4][2], bf[2][2];
#pragma unroll
      for (int j = 0; j < 4; ++j)
#pragma unroll
        for (int kk = 0; kk < 2; ++kk)
          af[j][kk] = rdfrag(Ac, wrow + (mq * 4 + j) * 16 + lr, kk);
#pragma unroll
      for (int j = 0; j < 2; ++j)
#pragma unroll
        for (int kk = 0; kk < 2; ++kk)
          bf[j][kk] = rdfrag(Bc, wcol + (nq * 2 + j) * 16 + lr, kk);
      if (pf && q == 0) {
        stage_half(A, brow, knx, An);
        stage_half(A, brow + 128, knx, An + 8192);
        stage_half(Bt, bcol, knx, Bn);
        if (BN == 256) stage_half(Bt, bcol + 128, knx, Bn + 8192);
      }
      __builtin_amdgcn_s_barrier();
      __builtin_amdgcn_s_setprio(1);
#pragma unroll
      for (int j = 0; j < 4; ++j)
#pragma unroll
        for (int j2 = 0; j2 < 2; ++j2)
#pragma unroll
          for (int kk = 0; kk < 2; ++kk)
            acc[mq * 4 + j][nq * 2 + j2] = __builtin_amdgcn_mfma_f32_16x16x32_bf16(
                af[j][kk], bf[j2][kk], acc[mq * 4 + j][nq * 2 + j2], 0, 0, 0);
      __builtin_amdgcn_s_setprio(0);
      if (q == NPH - 1) {
        asm volatile("s_waitcnt vmcnt(0)" ::: "memory");
        __builtin_amdgcn_s_barrier();
        __builtin_amdgcn_sched_barrier(0);
      } else {
        __builtin_amdgcn_s_barrier();
      }
    }
  }

  // ---- epilogue ----
  if (MODE == MODE_QKV && bcol >= 2048) {
    // V block: bias, transpose via LDS (reuse), coalesced write to vt (ob2)
    const int dbase = bcol - 2048;
#pragma unroll
    for (int m = 0; m < MREP; ++m) {
#pragma unroll
      for (int n = 0; n < 4; ++n) {
        const int cl = wcol + n * 16 + lr;
        const float bb = bias2[dbase + cl];
        uint16_t pk[4];
#pragma unroll
        for (int qi = 0; qi < 4; ++qi) pk[qi] = f2b(acc[m][n][qi] + bb);
        const int r0 = wrow + m * 16 + g * 4;
        *reinterpret_cast<uint2*>(&lds[cl * 264 + r0]) = *reinterpret_cast<uint2*>(pk);
      }
    }
    __syncthreads();
    const int bV = brow >> 11;
    const int tt0 = brow & 2047;
#pragma unroll
    for (int j = 0; j < 8; ++j) {
      int ch = j * 512 + t;
      int dl = ch >> 5, sc = ch & 31;
      short8 vv = *reinterpret_cast<const short8*>(&lds[dl * 264 + sc * 8]);
      int hd = dbase + dl;
      int h2 = hd >> 6, d = hd & 63;
      *reinterpret_cast<short8*>(ob2 + ((size_t)(bV * NH + h2)) * SEQ * DKH + (size_t)d * SEQ +
                                 tt0 + sc * 8) = vv;
    }
    return;
  }
#pragma unroll
  for (int m = 0; m < MREP; ++m) {
#pragma unroll
    for (int n = 0; n < 4; ++n) {
#pragma unroll
      for (int qi = 0; qi < 4; ++qi) {
        int r = brow + wrow + m * 16 + g * 4 + qi;
        int c = bcol + wcol + n * 16 + lr;
        float v = acc[m][n][qi];
        if (MODE == MODE_QKV) {  // Q or K block
          int which = c >> 10;
          int hd = c & 1023;
          const float* bp = which == 0 ? bias0 : bias1;
          v += bp[hd];
          if (which == 0) v *= 0.1803368801f;  // 1/sqrt(dk) * log2(e)
          uint16_t* dst = which == 0 ? ob0 : ob1;
          int b = r >> 11, tt = r & 2047;
          int h = hd >> 6, d = hd & 63;
          dst[((size_t)((b * NH + h) * SEQ + tt)) * DKH + d] = f2b(v);
        } else if (MODE == MODE_RELU) {
          v += bias0[c];
          v = fmaxf(v, 0.0f);
          ob0[(size_t)r * N + c] = f2b(v);
        } else {  // MODE_RAWB: bf16 raw out; bias+residual folded into LN
          ob0[(size_t)r * N + c] = f2b(v);
        }
      }
    }
  }
}

// ---------------- attention (converged): 32 q/wave, grid 1024, XCD-local ---------------
__global__ __launch_bounds__(256) void k_attn(const uint16_t* __restrict__ Qb,
                                              const uint16_t* __restrict__ Kb,
                                              const uint16_t* __restrict__ Vtg,
                                              uint16_t* __restrict__ ctx) {
  __shared__ __align__(16) uint16_t Ks[2][64 * 64];
  __shared__ __align__(16) uint16_t Vs[2][64 * 64];
  __shared__ float l_arr[4][32];
  const int o = blockIdx.x;
  const int wg = (o & 7) * 128 + (o >> 3);
  const int qt = wg & 15;
  const int bh = wg >> 4;
  const int b = bh >> 4, h = bh & 15;
  const uint16_t* Qp = Qb + (size_t)bh * SEQ * DKH;
  const uint16_t* Kp = Kb + (size_t)bh * SEQ * DKH;
  const uint16_t* Vp = Vtg + (size_t)bh * SEQ * DKH;  // [64][2048]
  const int t = threadIdx.x, w = t >> 6, l = t & 63;
  const int lo5 = l & 31, hh = l >> 5;
  const int qbase = qt * 128 + w * 32;

  short8 qf[4];
#pragma unroll
  for (int kc = 0; kc < 4; ++kc)
    qf[kc] = *reinterpret_cast<const short8*>(Qp + (size_t)(qbase + lo5) * DKH + kc * 16 + hh * 8);

  f32x16 oacc[2] = {};
  float lsum = 0.f;

  const int swz = ((l & 7) ^ ((l >> 3) & 7)) << 3;
  const int ci0 = w * 2, ci1 = w * 2 + 1;
  const int r0 = ci0 * 8 + (l >> 3), r1 = ci1 * 8 + (l >> 3);
  uint16_t* ldsK0 = &Ks[0][0] + ci0 * 512 + l * 8;
  uint16_t* ldsK1 = &Ks[0][0] + ci1 * 512 + l * 8;
  uint16_t* ldsV0 = &Vs[0][0] + ci0 * 512 + l * 8;
  uint16_t* ldsV1 = &Vs[0][0] + ci1 * 512 + l * 8;
  const uint16_t* gK0 = Kp + (size_t)r0 * DKH + swz;
  const uint16_t* gK1 = Kp + (size_t)r1 * DKH + swz;
  const uint16_t* gV0 = Vp + (size_t)r0 * SEQ + swz;
  const uint16_t* gV1 = Vp + (size_t)r1 * SEQ + swz;

  gload16(gK0, ldsK0);
  gload16(gK1, ldsK1);
  gload16(gV0, ldsV0);
  gload16(gV1, ldsV1);
  __syncthreads();

  for (int tile = 0; tile < 32; ++tile) {
    const int cur = tile & 1;
    if (tile < 31) {
      const int nxt = (cur ^ 1) * 4096;
      const size_t s0n = (size_t)(tile + 1) * 64;
      gload16(gK0 + s0n * DKH, ldsK0 + nxt);
      gload16(gK1 + s0n * DKH, ldsK1 + nxt);
      gload16(gV0 + s0n, ldsV0 + nxt);
      gload16(gV1 + s0n, ldsV1 + nxt);
    }
    const char* Kbuf = reinterpret_cast<const char*>(&Ks[cur][0]);
    const char* Vbuf = reinterpret_cast<const char*>(&Vs[cur][0]);

#pragma unroll
    for (int sblk = 0; sblk < 2; ++sblk) {
      short8 kf[4];
      const int krow = sblk * 32 + lo5;
      const int kxor = (krow & 7) << 4;
#pragma unroll
      for (int kc = 0; kc < 4; ++kc) {
        int cb = (kc * 32 + hh * 16) ^ kxor;
        kf[kc] = *reinterpret_cast<const short8*>(Kbuf + krow * 128 + cb);
      }
      short8 vf[2][2];
#pragma unroll
      for (int scl = 0; scl < 2; ++scl)
#pragma unroll
        for (int dblk = 0; dblk < 2; ++dblk) {
          int vrow = dblk * 32 + lo5;
          int cb = (sblk * 64 + scl * 32 + hh * 16) ^ ((vrow & 7) << 4);
          vf[scl][dblk] = *reinterpret_cast<const short8*>(Vbuf + vrow * 128 + cb);
        }

      f32x16 sa = {};
      __builtin_amdgcn_s_setprio(1);
#pragma unroll
      for (int kc = 0; kc < 4; ++kc)
        sa = __builtin_amdgcn_mfma_f32_32x32x16_bf16(kf[kc], qf[kc], sa, 0, 0, 0);
      __builtin_amdgcn_s_setprio(0);

      float p[16];
      float ls = 0.f;
#pragma unroll
      for (int r = 0; r < 16; ++r) {
        p[r] = __builtin_amdgcn_exp2f(sa[r]);
        ls += p[r];
      }
      lsum += ls;

      uint32_t clo[4], chi[4];
#pragma unroll
      for (int m = 0; m < 4; ++m) {
        asm("v_cvt_pk_bf16_f32 %0, %1, %2" : "=v"(clo[m]) : "v"(p[4 * m]), "v"(p[4 * m + 1]));
        asm("v_cvt_pk_bf16_f32 %0, %1, %2" : "=v"(chi[m]) : "v"(p[4 * m + 2]), "v"(p[4 * m + 3]));
      }

#pragma unroll
      for (int scl = 0; scl < 2; ++scl) {
        uint32_t a0 = clo[2 * scl], b0 = clo[2 * scl + 1];
        uint32_t a1 = chi[2 * scl], b1 = chi[2 * scl + 1];
        asm("v_permlane32_swap_b32 %0, %1" : "+v"(a0), "+v"(b0));
        asm("v_permlane32_swap_b32 %0, %1" : "+v"(a1), "+v"(b1));
        union {
          uint32_t u[4];
          short8 s;
        } pu;
        pu.u[0] = a0;
        pu.u[1] = a1;
        pu.u[2] = b0;
        pu.u[3] = b1;
        __builtin_amdgcn_s_setprio(1);
#pragma unroll
        for (int dblk = 0; dblk < 2; ++dblk)
          oacc[dblk] = __builtin_amdgcn_mfma_f32_32x32x16_bf16(pu.s, vf[scl][dblk], oacc[dblk], 0, 0, 0);
        __builtin_amdgcn_s_setprio(0);
      }
    }
    __syncthreads();
  }

  {
    float full = lsum + __shfl_xor(lsum, 32, 64);
    if (l < 32) l_arr[w][lo5] = full;
  }
#pragma unroll
  for (int r = 0; r < 16; ++r) {
    int q = (r & 3) + 8 * (r >> 2) + 4 * hh;
    float li = 1.0f / l_arr[w][q];
    int rowg = b * SEQ + qbase + q;
#pragma unroll
    for (int dblk = 0; dblk < 2; ++dblk) {
      int colg = h * DKH + dblk * 32 + lo5;
      ctx[(size_t)rowg * DMODEL + colg] = f2b(oacc[dblk][r] * li);
    }
  }
}

// ---------------- LayerNorm over (in + bias + res); in/res bf16-capable ----------------
template <bool WRITE_B, bool INBF, bool RESBF>
__global__ __launch_bounds__(256) void k_ln(const void* __restrict__ in,
                                            const float* __restrict__ bias,
                                            const void* __restrict__ res,
                                            const float* __restrict__ gam,
                                            const float* __restrict__ bet,
                                            float* __restrict__ outf,
                                            uint16_t* __restrict__ outb) {
  const int row = blockIdx.x;
  const int t = threadIdx.x, lane = t & 63, w = t >> 6;
  float4 v;
  if (INBF) {
    uint2 iu = reinterpret_cast<const uint2*>((const uint16_t*)in + (size_t)row * DMODEL)[t];
    const uint16_t* ip = reinterpret_cast<const uint16_t*>(&iu);
    v.x = b2f(ip[0]); v.y = b2f(ip[1]); v.z = b2f(ip[2]); v.w = b2f(ip[3]);
  } else {
    v = reinterpret_cast<const float4*>((const float*)in + (size_t)row * DMODEL)[t];
  }
  float4 bb0 = reinterpret_cast<const float4*>(bias)[t];
  float4 rr;
  if (RESBF) {
    uint2 ru = reinterpret_cast<const uint2*>((const uint16_t*)res + (size_t)row * DMODEL)[t];
    const uint16_t* rp = reinterpret_cast<const uint16_t*>(&ru);
    rr.x = b2f(rp[0]); rr.y = b2f(rp[1]); rr.z = b2f(rp[2]); rr.w = b2f(rp[3]);
  } else {
    rr = reinterpret_cast<const float4*>((const float*)res + (size_t)row * DMODEL)[t];
  }
  v.x += bb0.x + rr.x;
  v.y += bb0.y + rr.y;
  v.z += bb0.z + rr.z;
  v.w += bb0.w + rr.w;
  float s = v.x + v.y + v.z + v.w;
  float s2 = v.x * v.x + v.y * v.y + v.z * v.z + v.w * v.w;
#pragma unroll
  for (int off = 1; off < 64; off <<= 1) {
    s += __shfl_xor(s, off, 64);
    s2 += __shfl_xor(s2, off, 64);
  }
  __shared__ float rs[4], rq[4];
  if (lane == 0) {
    rs[w] = s;
    rq[w] = s2;
  }
  __syncthreads();
  float ts = rs[0] + rs[1] + rs[2] + rs[3];
  float tq = rq[0] + rq[1] + rq[2] + rq[3];
  const float inv = 1.0f / DMODEL;
  float mu = ts * inv;
  float var = tq * inv - mu * mu;
  float rstd = rsqrtf(var + 1e-5f);
  float4 gg = reinterpret_cast<const float4*>(gam)[t];
  float4 bb = reinterpret_cast<const float4*>(bet)[t];
  float4 y;
  y.x = (v.x - mu) * rstd * gg.x + bb.x;
  y.y = (v.y - mu) * rstd * gg.y + bb.y;
  y.z = (v.z - mu) * rstd * gg.z + bb.z;
  y.w = (v.w - mu) * rstd * gg.w + bb.w;
  if (WRITE_B) {
    uint16_t oo[4] = {f2b(y.x), f2b(y.y), f2b(y.z), f2b(y.w)};
    reinterpret_cast<uint2*>(outb)[(size_t)row * 256 + t] = *reinterpret_cast<uint2*>(oo);
  } else {
    reinterpret_cast<float4*>(outf)[(size_t)row * 256 + t] = y;
  }
}

extern "C" void kernel_launch(void* const* d_in, const int* in_sizes, int n_in, void* d_out,
                              int out_size, void* d_ws, size_t ws_size, hipStream_t stream) {
  const float* x = (const float*)d_in[0];
  const float* Wq = (const float*)d_in[1];
  const float* bq = (const float*)d_in[2];
  const float* Wk = (const float*)d_in[3];
  const float* bk = (const float*)d_in[4];
  const float* Wv = (const float*)d_in[5];
  const float* bv = (const float*)d_in[6];
  const float* Wo = (const float*)d_in[7];
  const float* bo = (const float*)d_in[8];
  const float* g1 = (const float*)d_in[9];
  const float* be1 = (const float*)d_in[10];
  const float* W1 = (const float*)d_in[11];
  const float* b1 = (const float*)d_in[12];
  const float* W2 = (const float*)d_in[13];
  const float* b2 = (const float*)d_in[14];
  const float* g2 = (const float*)d_in[15];
  const float* be2 = (const float*)d_in[16];

  char* ws = (char*)d_ws;
  size_t off = 0;
  auto alloc = [&](size_t bytes) {
    char* p = ws + off;
    off += (bytes + 255) & ~(size_t)255;
    return p;
  };
  uint16_t* wt_qkv = (uint16_t*)alloc(3072ull * 1024 * 2);
  uint16_t* wt_o = (uint16_t*)alloc(1024ull * 1024 * 2);
  uint16_t* wt_1 = (uint16_t*)alloc(4096ull * 1024 * 2);
  uint16_t* wt_2 = (uint16_t*)alloc(1024ull * 4096 * 2);
  uint16_t* xb = (uint16_t*)alloc(8192ull * 1024 * 2);     // x bf16 (stays live: LN1 residual)
  uint16_t* ctx = (uint16_t*)alloc(8192ull * 1024 * 2);    // attention output (own buffer!)
  uint16_t* bfout = (uint16_t*)alloc(8192ull * 1024 * 2);  // Wo out bf16, then FFN2 out bf16
  uint16_t* vt = (uint16_t*)alloc(8192ull * 1024 * 2);     // V^T (written by QKV epilogue)
  char* big = alloc(16777216ull + 67108864ull);            // Q(16)+K(16) -> x1b(16)+h(64)
  uint16_t* Qbuf = (uint16_t*)big;
  uint16_t* Kbuf = (uint16_t*)(big + 16777216ull);
  uint16_t* x1b = (uint16_t*)big;                   // alias: Q dead after attention
  uint16_t* hbuf = (uint16_t*)(big + 16777216ull);  // alias: K dead after attention
  (void)ws_size;

  // 1. all prep (weight transposes + x cast) in one launch
  k_prep<<<20480, 256, 0, stream>>>(Wq, Wk, Wv, Wo, W1, W2, x, wt_qkv, wt_o, wt_1, wt_2, xb);
  // 2. QKV projection; V written pre-transposed into vt by the fused epilogue
  k_gemm2<128, MODE_QKV><<<768, 512, 0, stream>>>(
      xb, wt_qkv, 8192, 3072, 1024, 24, bq, bk, bv, Qbuf, Kbuf, vt, nullptr);
  // 3. attention -> ctx
  k_attn<<<1024, 256, 0, stream>>>(Qbuf, Kbuf, vt, ctx);
  // 4. Wo projection -> bfout (bf16)
  k_gemm2<128, MODE_RAWB><<<256, 512, 0, stream>>>(
      ctx, wt_o, 8192, 1024, 1024, 8, nullptr, nullptr, nullptr, bfout, nullptr, nullptr, nullptr);
  // 5. LN1(bfout + bo + xb) -> x1b (bf16)
  k_ln<true, true, true><<<8192, 256, 0, stream>>>(bfout, bo, xb, g1, be1, nullptr, x1b);
  // 6. FFN1: relu(x1 @ W1 + b1) -> h bf16
  k_gemm2<256, MODE_RELU><<<512, 512, 0, stream>>>(
      x1b, wt_1, 8192, 4096, 1024, 16, b1, nullptr, nullptr, hbuf, nullptr, nullptr, nullptr);
  // 7. FFN2 -> bfout (bf16)
  k_gemm2<128, MODE_RAWB><<<256, 512, 0, stream>>>(
      hbuf, wt_2, 8192, 1024, 4096, 8, nullptr, nullptr, nullptr, bfout, nullptr, nullptr, nullptr);
  // 8. LN2(bfout + b2 + x1b) -> output (f32)
  k_ln<false, true, true><<<8192, 256, 0, stream>>>(bfout, b2, x1b, g2, be2, (float*)d_out, nullptr);
}

// Round 14
// 382.973 us; speedup vs baseline: 1.1010x; 1.0166x over previous
//
#include <hip/hip_runtime.h>
#include <hip/hip_bf16.h>
#include <stdint.h>

typedef __attribute__((ext_vector_type(8))) short short8;
typedef __attribute__((ext_vector_type(4))) float f32x4;
typedef __attribute__((ext_vector_type(16))) float f32x16;

#define SEQ 2048
#define DMODEL 1024
#define NH 16
#define DKH 64

__device__ __forceinline__ uint16_t f2b(float f) {
  uint32_t u = __float_as_uint(f);
  uint32_t r = (u + 0x7fff + ((u >> 16) & 1)) >> 16;
  return (uint16_t)r;
}
__device__ __forceinline__ float b2f(uint16_t u) {
  return __uint_as_float(((uint32_t)u) << 16);
}

__device__ __forceinline__ void gload16(const uint16_t* g, uint16_t* l) {
  __builtin_amdgcn_global_load_lds((const __attribute__((address_space(1))) void*)g,
                                   (__attribute__((address_space(3))) void*)l, 16, 0, 0);
}

// ---------------- all weight cast+transposes AND x-cast in ONE kernel ----------------
__global__ __launch_bounds__(256) void k_prep(
    const float* __restrict__ Wq, const float* __restrict__ Wk, const float* __restrict__ Wv,
    const float* __restrict__ Wo, const float* __restrict__ W1, const float* __restrict__ W2,
    const float* __restrict__ x, uint16_t* __restrict__ wt_qkv, uint16_t* __restrict__ wt_o,
    uint16_t* __restrict__ wt_1, uint16_t* __restrict__ wt_2, uint16_t* __restrict__ xb) {
  const int id = blockIdx.x;
  if (id >= 12288) {  // castx part
    int i = (id - 12288) * 256 + threadIdx.x;
    float4 v = reinterpret_cast<const float4*>(x)[i];
    uint16_t o[4] = {f2b(v.x), f2b(v.y), f2b(v.z), f2b(v.w)};
    reinterpret_cast<uint2*>(xb)[i] = *reinterpret_cast<uint2*>(o);
    return;
  }
  __shared__ float tile[32][33];
  const float* W;
  uint16_t* Wt;
  int K, N, bx, by;
  if (id < 4096) {
    int wsel = id >> 10, r = id & 1023;
    K = 1024; N = 1024; bx = r & 31; by = r >> 5;
    W = wsel == 0 ? Wq : (wsel == 1 ? Wk : (wsel == 2 ? Wv : Wo));
    Wt = wsel == 3 ? wt_o : wt_qkv + wsel * 1024 * 1024;
  } else if (id < 8192) {
    int r = id - 4096;
    K = 1024; N = 4096; bx = r & 127; by = r >> 7;
    W = W1; Wt = wt_1;
  } else {
    int r = id - 8192;
    K = 4096; N = 1024; bx = r & 31; by = r >> 5;
    W = W2; Wt = wt_2;
  }
  const int n0 = bx * 32, k0 = by * 32;
  const int tx = threadIdx.x & 31, ty = threadIdx.x >> 5;
#pragma unroll
  for (int i = 0; i < 32; i += 8)
    tile[ty + i][tx] = W[(size_t)(k0 + ty + i) * N + n0 + tx];
  __syncthreads();
#pragma unroll
  for (int i = 0; i < 32; i += 8)
    Wt[(size_t)(n0 + ty + i) * K + k0 + tx] = f2b(tile[tx][ty + i]);
}

// ---------------- GEMM v4: counted-vmcnt half-pipelined, 1 barrier/phase ---------------
// Wave frag remap so phase (mq,nq) consumes exactly A-half(mq) + B-half(nq) uniformly.
// Uniform per-thread load order (A0,B0,B1,A1 per tile for BN=256; A0,B,A1 for BN=128)
// makes per-wave vmcnt(N)+barrier a block-wide staging guarantee. Never drains to 0
// in the main loop (except last-tile tail waits).
#define MODE_QKV 0
#define MODE_RAWB 1
#define MODE_RELU 2

template <int BN, int MODE>
__global__ __launch_bounds__(512, 2) void k_gemm2(
    const uint16_t* __restrict__ A, const uint16_t* __restrict__ Bt, int M, int N, int K,
    int nx, const float* __restrict__ bias0, const float* __restrict__ bias1,
    const float* __restrict__ bias2, uint16_t* __restrict__ ob0, uint16_t* __restrict__ ob1,
    uint16_t* __restrict__ ob2, float* __restrict__ of) {
  constexpr int ASZ = 256 * 64;
  constexpr int BSZ = BN * 64;
  __shared__ __align__(16) uint16_t lds[2 * (ASZ + BSZ)];
  uint16_t* const Abase = lds;
  uint16_t* const Bbase = lds + 2 * ASZ;
  constexpr int WN = (BN == 256) ? 4 : 2;
  constexpr int MREP = (BN == 256) ? 8 : 4;
  constexpr int NPH = (BN == 256) ? 4 : 2;
  constexpr int MJ = (BN == 256) ? 4 : 2;  // A frags per phase
  constexpr int NJ = (BN == 256) ? 2 : 4;  // B frags per phase
  const int o = blockIdx.x;
  const int chunk = gridDim.x >> 3;
  const int wg = (o & 7) * chunk + (o >> 3);
  const int brow = (wg / nx) << 8;
  const int bcol = (wg % nx) * BN;
  const int t = threadIdx.x;
  const int wid = t >> 6, l = t & 63, g = l >> 4, lr = l & 15;
  const int wr = wid / WN, wc = wid % WN;

  auto rowb = [&](int m) {
    return (BN == 256) ? ((m >> 2) * 128 + wr * 64 + (m & 3) * 16)
                       : ((m >> 1) * 128 + wr * 32 + (m & 1) * 16);
  };
  auto colb = [&](int n) {
    return (BN == 256) ? ((n >> 1) * 128 + wc * 32 + (n & 1) * 16) : (wc * 64 + n * 16);
  };

  const int srow = t >> 3;
  const int ss0 = (t & 7) ^ (srow & 7);
  const int ss1 = (t & 7) ^ ((srow + 64) & 7);

  auto stage_half = [&](const uint16_t* gsrc, int grow0, int kk, uint16_t* ldst) {
    gload16(gsrc + (size_t)(grow0 + srow) * K + kk + ss0 * 8, ldst + t * 8);
    gload16(gsrc + (size_t)(grow0 + srow + 64) * K + kk + ss1 * 8, ldst + 4096 + t * 8);
  };
  auto rdfrag = [&](const uint16_t* buf, int ar, int kk) -> short8 {
    int slot = ((kk << 2) + g) ^ (ar & 7);
    return *reinterpret_cast<const short8*>(buf + ar * 64 + slot * 8);
  };

  f32x4 acc[MREP][4] = {};
  const int nt = K >> 6;

  // prologue: stage tile 0 in the steady-state order
  if (BN == 256) {
    stage_half(A, brow, 0, Abase);                // A0
    stage_half(Bt, bcol, 0, Bbase);               // B0
    stage_half(Bt, bcol + 128, 0, Bbase + 8192);  // B1
    stage_half(A, brow + 128, 0, Abase + 8192);   // A1
  } else {
    stage_half(A, brow, 0, Abase);               // A0
    stage_half(Bt, bcol, 0, Bbase);              // B (both halves, one call)
    stage_half(A, brow + 128, 0, Abase + 8192);  // A1
  }

  for (int kt = 0; kt < nt; ++kt) {
    const int cur = kt & 1;
    const uint16_t* Ac = Abase + cur * ASZ;
    const uint16_t* Bc = Bbase + cur * BSZ;
    uint16_t* An = Abase + (cur ^ 1) * ASZ;
    uint16_t* Bn = Bbase + (cur ^ 1) * BSZ;
    const bool pf = (kt + 1 < nt);
    const int knx = (kt + 1) << 6;
#pragma unroll
    for (int q = 0; q < NPH; ++q) {
      // --- counted wait (ledger: see header comment) + one barrier per phase ---
      if (BN == 256) {
        if (q == 0) {
          asm volatile("s_waitcnt vmcnt(4)" ::: "memory");
        } else if (q == 1) {
          if (pf) asm volatile("s_waitcnt vmcnt(4)" ::: "memory");
          else asm volatile("s_waitcnt vmcnt(2)" ::: "memory");
        } else if (q == 2) {
          if (pf) asm volatile("s_waitcnt vmcnt(4)" ::: "memory");
          else asm volatile("s_waitcnt vmcnt(0)" ::: "memory");
        }
      } else {
        if (q == 0) {
          asm volatile("s_waitcnt vmcnt(2)" ::: "memory");
        } else {
          if (pf) asm volatile("s_waitcnt vmcnt(4)" ::: "memory");
          else asm volatile("s_waitcnt vmcnt(0)" ::: "memory");
        }
      }
      __builtin_amdgcn_s_barrier();
      __builtin_amdgcn_sched_barrier(0);
      // --- stage next tile's half (uniform order across all threads) ---
      if (pf) {
        if (BN == 256) {
          if (q == 0) stage_half(A, brow, knx, An);
          else if (q == 1) stage_half(Bt, bcol, knx, Bn);
          else if (q == 2) stage_half(Bt, bcol + 128, knx, Bn + 8192);
          else stage_half(A, brow + 128, knx, An + 8192);
        } else {
          if (q == 0) {
            stage_half(A, brow, knx, An);
            stage_half(Bt, bcol, knx, Bn);
          } else {
            stage_half(A, brow + 128, knx, An + 8192);
          }
        }
      }
      // --- frag reads (current tile, halves covered by the wait) + MFMA ---
      const int mq = (BN == 256) ? (q >> 1) : q;
      const int nq = (BN == 256) ? (q & 1) : 0;
      short8 af[MJ][2], bf[NJ][2];
#pragma unroll
      for (int j = 0; j < MJ; ++j)
#pragma unroll
        for (int kk = 0; kk < 2; ++kk)
          af[j][kk] = rdfrag(Ac, rowb(mq * MJ + j) + lr, kk);
#pragma unroll
      for (int j2 = 0; j2 < NJ; ++j2)
#pragma unroll
        for (int kk = 0; kk < 2; ++kk)
          bf[j2][kk] = rdfrag(Bc, colb(nq * NJ + j2) + lr, kk);
      __builtin_amdgcn_s_setprio(1);
#pragma unroll
      for (int j = 0; j < MJ; ++j)
#pragma unroll
        for (int j2 = 0; j2 < NJ; ++j2)
#pragma unroll
          for (int kk = 0; kk < 2; ++kk)
            acc[mq * MJ + j][nq * NJ + j2] = __builtin_amdgcn_mfma_f32_16x16x32_bf16(
                af[j][kk], bf[j2][kk], acc[mq * MJ + j][nq * NJ + j2], 0, 0, 0);
      __builtin_amdgcn_s_setprio(0);
    }
  }

  // ---- epilogue ----
  if (MODE == MODE_QKV && bcol >= 2048) {
    // V block: bias, transpose via LDS (reuse), coalesced write to vt (ob2)
    const int dbase = bcol - 2048;
    __syncthreads();  // all MFMA/frag reads done before LDS reuse
#pragma unroll
    for (int m = 0; m < MREP; ++m) {
#pragma unroll
      for (int n = 0; n < 4; ++n) {
        const int cl = colb(n) + lr;
        const float bb = bias2[dbase + cl];
        uint16_t pk[4];
#pragma unroll
        for (int qi = 0; qi < 4; ++qi) pk[qi] = f2b(acc[m][n][qi] + bb);
        const int r0 = rowb(m) + g * 4;
        *reinterpret_cast<uint2*>(&lds[cl * 264 + r0]) = *reinterpret_cast<uint2*>(pk);
      }
    }
    __syncthreads();
    const int bV = brow >> 11;
    const int tt0 = brow & 2047;
#pragma unroll
    for (int j = 0; j < 8; ++j) {
      int ch = j * 512 + t;
      int dl = ch >> 5, sc = ch & 31;
      short8 vv = *reinterpret_cast<const short8*>(&lds[dl * 264 + sc * 8]);
      int hd = dbase + dl;
      int h2 = hd >> 6, d = hd & 63;
      *reinterpret_cast<short8*>(ob2 + ((size_t)(bV * NH + h2)) * SEQ * DKH + (size_t)d * SEQ +
                                 tt0 + sc * 8) = vv;
    }
    return;
  }
#pragma unroll
  for (int m = 0; m < MREP; ++m) {
#pragma unroll
    for (int n = 0; n < 4; ++n) {
#pragma unroll
      for (int qi = 0; qi < 4; ++qi) {
        int r = brow + rowb(m) + g * 4 + qi;
        int c = bcol + colb(n) + lr;
        float v = acc[m][n][qi];
        if (MODE == MODE_QKV) {  // Q or K block
          int which = c >> 10;
          int hd = c & 1023;
          const float* bp = which == 0 ? bias0 : bias1;
          v += bp[hd];
          if (which == 0) v *= 0.1803368801f;  // 1/sqrt(dk) * log2(e)
          uint16_t* dst = which == 0 ? ob0 : ob1;
          int b = r >> 11, tt = r & 2047;
          int h = hd >> 6, d = hd & 63;
          dst[((size_t)((b * NH + h) * SEQ + tt)) * DKH + d] = f2b(v);
        } else if (MODE == MODE_RELU) {
          v += bias0[c];
          v = fmaxf(v, 0.0f);
          ob0[(size_t)r * N + c] = f2b(v);
        } else {  // MODE_RAWB
          ob0[(size_t)r * N + c] = f2b(v);
        }
      }
    }
  }
}

// ---------------- attention (converged): 32 q/wave, grid 1024, XCD-local ---------------
__global__ __launch_bounds__(256) void k_attn(const uint16_t* __restrict__ Qb,
                                              const uint16_t* __restrict__ Kb,
                                              const uint16_t* __restrict__ Vtg,
                                              uint16_t* __restrict__ ctx) {
  __shared__ __align__(16) uint16_t Ks[2][64 * 64];
  __shared__ __align__(16) uint16_t Vs[2][64 * 64];
  __shared__ float l_arr[4][32];
  const int o = blockIdx.x;
  const int wg = (o & 7) * 128 + (o >> 3);
  const int qt = wg & 15;
  const int bh = wg >> 4;
  const int b = bh >> 4, h = bh & 15;
  const uint16_t* Qp = Qb + (size_t)bh * SEQ * DKH;
  const uint16_t* Kp = Kb + (size_t)bh * SEQ * DKH;
  const uint16_t* Vp = Vtg + (size_t)bh * SEQ * DKH;  // [64][2048]
  const int t = threadIdx.x, w = t >> 6, l = t & 63;
  const int lo5 = l & 31, hh = l >> 5;
  const int qbase = qt * 128 + w * 32;

  short8 qf[4];
#pragma unroll
  for (int kc = 0; kc < 4; ++kc)
    qf[kc] = *reinterpret_cast<const short8*>(Qp + (size_t)(qbase + lo5) * DKH + kc * 16 + hh * 8);

  f32x16 oacc[2] = {};
  float lsum = 0.f;

  const int swz = ((l & 7) ^ ((l >> 3) & 7)) << 3;
  const int ci0 = w * 2, ci1 = w * 2 + 1;
  const int r0 = ci0 * 8 + (l >> 3), r1 = ci1 * 8 + (l >> 3);
  uint16_t* ldsK0 = &Ks[0][0] + ci0 * 512 + l * 8;
  uint16_t* ldsK1 = &Ks[0][0] + ci1 * 512 + l * 8;
  uint16_t* ldsV0 = &Vs[0][0] + ci0 * 512 + l * 8;
  uint16_t* ldsV1 = &Vs[0][0] + ci1 * 512 + l * 8;
  const uint16_t* gK0 = Kp + (size_t)r0 * DKH + swz;
  const uint16_t* gK1 = Kp + (size_t)r1 * DKH + swz;
  const uint16_t* gV0 = Vp + (size_t)r0 * SEQ + swz;
  const uint16_t* gV1 = Vp + (size_t)r1 * SEQ + swz;

  gload16(gK0, ldsK0);
  gload16(gK1, ldsK1);
  gload16(gV0, ldsV0);
  gload16(gV1, ldsV1);
  __syncthreads();

  for (int tile = 0; tile < 32; ++tile) {
    const int cur = tile & 1;
    if (tile < 31) {
      const int nxt = (cur ^ 1) * 4096;
      const size_t s0n = (size_t)(tile + 1) * 64;
      gload16(gK0 + s0n * DKH, ldsK0 + nxt);
      gload16(gK1 + s0n * DKH, ldsK1 + nxt);
      gload16(gV0 + s0n, ldsV0 + nxt);
      gload16(gV1 + s0n, ldsV1 + nxt);
    }
    const char* Kbuf = reinterpret_cast<const char*>(&Ks[cur][0]);
    const char* Vbuf = reinterpret_cast<const char*>(&Vs[cur][0]);

#pragma unroll
    for (int sblk = 0; sblk < 2; ++sblk) {
      short8 kf[4];
      const int krow = sblk * 32 + lo5;
      const int kxor = (krow & 7) << 4;
#pragma unroll
      for (int kc = 0; kc < 4; ++kc) {
        int cb = (kc * 32 + hh * 16) ^ kxor;
        kf[kc] = *reinterpret_cast<const short8*>(Kbuf + krow * 128 + cb);
      }
      short8 vf[2][2];
#pragma unroll
      for (int scl = 0; scl < 2; ++scl)
#pragma unroll
        for (int dblk = 0; dblk < 2; ++dblk) {
          int vrow = dblk * 32 + lo5;
          int cb = (sblk * 64 + scl * 32 + hh * 16) ^ ((vrow & 7) << 4);
          vf[scl][dblk] = *reinterpret_cast<const short8*>(Vbuf + vrow * 128 + cb);
        }

      f32x16 sa = {};
      __builtin_amdgcn_s_setprio(1);
#pragma unroll
      for (int kc = 0; kc < 4; ++kc)
        sa = __builtin_amdgcn_mfma_f32_32x32x16_bf16(kf[kc], qf[kc], sa, 0, 0, 0);
      __builtin_amdgcn_s_setprio(0);

      float p[16];
      float ls = 0.f;
#pragma unroll
      for (int r = 0; r < 16; ++r) {
        p[r] = __builtin_amdgcn_exp2f(sa[r]);
        ls += p[r];
      }
      lsum += ls;

      uint32_t clo[4], chi[4];
#pragma unroll
      for (int m = 0; m < 4; ++m) {
        asm("v_cvt_pk_bf16_f32 %0, %1, %2" : "=v"(clo[m]) : "v"(p[4 * m]), "v"(p[4 * m + 1]));
        asm("v_cvt_pk_bf16_f32 %0, %1, %2" : "=v"(chi[m]) : "v"(p[4 * m + 2]), "v"(p[4 * m + 3]));
      }

#pragma unroll
      for (int scl = 0; scl < 2; ++scl) {
        uint32_t a0 = clo[2 * scl], b0 = clo[2 * scl + 1];
        uint32_t a1 = chi[2 * scl], b1 = chi[2 * scl + 1];
        asm("v_permlane32_swap_b32 %0, %1" : "+v"(a0), "+v"(b0));
        asm("v_permlane32_swap_b32 %0, %1" : "+v"(a1), "+v"(b1));
        union {
          uint32_t u[4];
          short8 s;
        } pu;
        pu.u[0] = a0;
        pu.u[1] = a1;
        pu.u[2] = b0;
        pu.u[3] = b1;
        __builtin_amdgcn_s_setprio(1);
#pragma unroll
        for (int dblk = 0; dblk < 2; ++dblk)
          oacc[dblk] = __builtin_amdgcn_mfma_f32_32x32x16_bf16(pu.s, vf[scl][dblk], oacc[dblk], 0, 0, 0);
        __builtin_amdgcn_s_setprio(0);
      }
    }
    __syncthreads();
  }

  {
    float full = lsum + __shfl_xor(lsum, 32, 64);
    if (l < 32) l_arr[w][lo5] = full;
  }
#pragma unroll
  for (int r = 0; r < 16; ++r) {
    int q = (r & 3) + 8 * (r >> 2) + 4 * hh;
    float li = 1.0f / l_arr[w][q];
    int rowg = b * SEQ + qbase + q;
#pragma unroll
    for (int dblk = 0; dblk < 2; ++dblk) {
      int colg = h * DKH + dblk * 32 + lo5;
      ctx[(size_t)rowg * DMODEL + colg] = f2b(oacc[dblk][r] * li);
    }
  }
}

// ---------------- LayerNorm over (in + bias + res); in/res bf16-capable ----------------
template <bool WRITE_B, bool INBF, bool RESBF>
__global__ __launch_bounds__(256) void k_ln(const void* __restrict__ in,
                                            const float* __restrict__ bias,
                                            const void* __restrict__ res,
                                            const float* __restrict__ gam,
                                            const float* __restrict__ bet,
                                            float* __restrict__ outf,
                                            uint16_t* __restrict__ outb) {
  const int row = blockIdx.x;
  const int t = threadIdx.x, lane = t & 63, w = t >> 6;
  float4 v;
  if (INBF) {
    uint2 iu = reinterpret_cast<const uint2*>((const uint16_t*)in + (size_t)row * DMODEL)[t];
    const uint16_t* ip = reinterpret_cast<const uint16_t*>(&iu);
    v.x = b2f(ip[0]); v.y = b2f(ip[1]); v.z = b2f(ip[2]); v.w = b2f(ip[3]);
  } else {
    v = reinterpret_cast<const float4*>((const float*)in + (size_t)row * DMODEL)[t];
  }
  float4 bb0 = reinterpret_cast<const float4*>(bias)[t];
  float4 rr;
  if (RESBF) {
    uint2 ru = reinterpret_cast<const uint2*>((const uint16_t*)res + (size_t)row * DMODEL)[t];
    const uint16_t* rp = reinterpret_cast<const uint16_t*>(&ru);
    rr.x = b2f(rp[0]); rr.y = b2f(rp[1]); rr.z = b2f(rp[2]); rr.w = b2f(rp[3]);
  } else {
    rr = reinterpret_cast<const float4*>((const float*)res + (size_t)row * DMODEL)[t];
  }
  v.x += bb0.x + rr.x;
  v.y += bb0.y + rr.y;
  v.z += bb0.z + rr.z;
  v.w += bb0.w + rr.w;
  float s = v.x + v.y + v.z + v.w;
  float s2 = v.x * v.x + v.y * v.y + v.z * v.z + v.w * v.w;
#pragma unroll
  for (int off = 1; off < 64; off <<= 1) {
    s += __shfl_xor(s, off, 64);
    s2 += __shfl_xor(s2, off, 64);
  }
  __shared__ float rs[4], rq[4];
  if (lane == 0) {
    rs[w] = s;
    rq[w] = s2;
  }
  __syncthreads();
  float ts = rs[0] + rs[1] + rs[2] + rs[3];
  float tq = rq[0] + rq[1] + rq[2] + rq[3];
  const float inv = 1.0f / DMODEL;
  float mu = ts * inv;
  float var = tq * inv - mu * mu;
  float rstd = rsqrtf(var + 1e-5f);
  float4 gg = reinterpret_cast<const float4*>(gam)[t];
  float4 bb = reinterpret_cast<const float4*>(bet)[t];
  float4 y;
  y.x = (v.x - mu) * rstd * gg.x + bb.x;
  y.y = (v.y - mu) * rstd * gg.y + bb.y;
  y.z = (v.z - mu) * rstd * gg.z + bb.z;
  y.w = (v.w - mu) * rstd * gg.w + bb.w;
  if (WRITE_B) {
    uint16_t oo[4] = {f2b(y.x), f2b(y.y), f2b(y.z), f2b(y.w)};
    reinterpret_cast<uint2*>(outb)[(size_t)row * 256 + t] = *reinterpret_cast<uint2*>(oo);
  } else {
    reinterpret_cast<float4*>(outf)[(size_t)row * 256 + t] = y;
  }
}

extern "C" void kernel_launch(void* const* d_in, const int* in_sizes, int n_in, void* d_out,
                              int out_size, void* d_ws, size_t ws_size, hipStream_t stream) {
  const float* x = (const float*)d_in[0];
  const float* Wq = (const float*)d_in[1];
  const float* bq = (const float*)d_in[2];
  const float* Wk = (const float*)d_in[3];
  const float* bk = (const float*)d_in[4];
  const float* Wv = (const float*)d_in[5];
  const float* bv = (const float*)d_in[6];
  const float* Wo = (const float*)d_in[7];
  const float* bo = (const float*)d_in[8];
  const float* g1 = (const float*)d_in[9];
  const float* be1 = (const float*)d_in[10];
  const float* W1 = (const float*)d_in[11];
  const float* b1 = (const float*)d_in[12];
  const float* W2 = (const float*)d_in[13];
  const float* b2 = (const float*)d_in[14];
  const float* g2 = (const float*)d_in[15];
  const float* be2 = (const float*)d_in[16];

  char* ws = (char*)d_ws;
  size_t off = 0;
  auto alloc = [&](size_t bytes) {
    char* p = ws + off;
    off += (bytes + 255) & ~(size_t)255;
    return p;
  };
  uint16_t* wt_qkv = (uint16_t*)alloc(3072ull * 1024 * 2);
  uint16_t* wt_o = (uint16_t*)alloc(1024ull * 1024 * 2);
  uint16_t* wt_1 = (uint16_t*)alloc(4096ull * 1024 * 2);
  uint16_t* wt_2 = (uint16_t*)alloc(1024ull * 4096 * 2);
  uint16_t* xb = (uint16_t*)alloc(8192ull * 1024 * 2);     // x bf16 (live: LN1 residual)
  uint16_t* ctx = (uint16_t*)alloc(8192ull * 1024 * 2);    // attention output
  uint16_t* bfout = (uint16_t*)alloc(8192ull * 1024 * 2);  // Wo out bf16, then FFN2 out bf16
  uint16_t* vt = (uint16_t*)alloc(8192ull * 1024 * 2);     // V^T (written by QKV epilogue)
  char* big = alloc(16777216ull + 67108864ull);            // Q(16)+K(16) -> x1b(16)+h(64)
  uint16_t* Qbuf = (uint16_t*)big;
  uint16_t* Kbuf = (uint16_t*)(big + 16777216ull);
  uint16_t* x1b = (uint16_t*)big;                   // alias: Q dead after attention
  uint16_t* hbuf = (uint16_t*)(big + 16777216ull);  // alias: K dead after attention
  (void)ws_size;

  // 1. all prep (weight transposes + x cast) in one launch
  k_prep<<<20480, 256, 0, stream>>>(Wq, Wk, Wv, Wo, W1, W2, x, wt_qkv, wt_o, wt_1, wt_2, xb);
  // 2. QKV projection; V written pre-transposed into vt by the fused epilogue
  k_gemm2<128, MODE_QKV><<<768, 512, 0, stream>>>(
      xb, wt_qkv, 8192, 3072, 1024, 24, bq, bk, bv, Qbuf, Kbuf, vt, nullptr);
  // 3. attention -> ctx
  k_attn<<<1024, 256, 0, stream>>>(Qbuf, Kbuf, vt, ctx);
  // 4. Wo projection -> bfout (bf16)
  k_gemm2<128, MODE_RAWB><<<256, 512, 0, stream>>>(
      ctx, wt_o, 8192, 1024, 1024, 8, nullptr, nullptr, nullptr, bfout, nullptr, nullptr, nullptr);
  // 5. LN1(bfout + bo + xb) -> x1b (bf16)
  k_ln<true, true, true><<<8192, 256, 0, stream>>>(bfout, bo, xb, g1, be1, nullptr, x1b);
  // 6. FFN1: relu(x1 @ W1 + b1) -> h bf16
  k_gemm2<256, MODE_RELU><<<512, 512, 0, stream>>>(
      x1b, wt_1, 8192, 4096, 1024, 16, b1, nullptr, nullptr, hbuf, nullptr, nullptr, nullptr);
  // 7. FFN2 -> bfout (bf16)
  k_gemm2<128, MODE_RAWB><<<256, 512, 0, stream>>>(
      hbuf, wt_2, 8192, 1024, 4096, 8, nullptr, nullptr, nullptr, bfout, nullptr, nullptr, nullptr);
  // 8. LN2(bfout + b2 + x1b) -> output (f32)
  k_ln<false, true, true><<<8192, 256, 0, stream>>>(bfout, b2, x1b, g2, be2, (float*)d_out, nullptr);
}

// Round 15
// 382.179 us; speedup vs baseline: 1.1033x; 1.0021x over previous
//
#include <hip/hip_runtime.h>
#include <hip/hip_bf16.h>
#include <stdint.h>

typedef __attribute__((ext_vector_type(8))) short short8;
typedef __attribute__((ext_vector_type(4))) float f32x4;
typedef __attribute__((ext_vector_type(16))) float f32x16;

#define SEQ 2048
#define DMODEL 1024
#define NH 16
#define DKH 64

__device__ __forceinline__ uint16_t f2b(float f) {
  uint32_t u = __float_as_uint(f);
  uint32_t r = (u + 0x7fff + ((u >> 16) & 1)) >> 16;
  return (uint16_t)r;
}
__device__ __forceinline__ float b2f(uint16_t u) {
  return __uint_as_float(((uint32_t)u) << 16);
}

__device__ __forceinline__ void gload16(const uint16_t* g, uint16_t* l) {
  __builtin_amdgcn_global_load_lds((const __attribute__((address_space(1))) void*)g,
                                   (__attribute__((address_space(3))) void*)l, 16, 0, 0);
}

// ---------------- all weight cast+transposes AND x-cast in ONE kernel ----------------
__global__ __launch_bounds__(256) void k_prep(
    const float* __restrict__ Wq, const float* __restrict__ Wk, const float* __restrict__ Wv,
    const float* __restrict__ Wo, const float* __restrict__ W1, const float* __restrict__ W2,
    const float* __restrict__ x, uint16_t* __restrict__ wt_qkv, uint16_t* __restrict__ wt_o,
    uint16_t* __restrict__ wt_1, uint16_t* __restrict__ wt_2, uint16_t* __restrict__ xb) {
  const int id = blockIdx.x;
  if (id >= 12288) {  // castx part
    int i = (id - 12288) * 256 + threadIdx.x;
    float4 v = reinterpret_cast<const float4*>(x)[i];
    uint16_t o[4] = {f2b(v.x), f2b(v.y), f2b(v.z), f2b(v.w)};
    reinterpret_cast<uint2*>(xb)[i] = *reinterpret_cast<uint2*>(o);
    return;
  }
  __shared__ float tile[32][33];
  const float* W;
  uint16_t* Wt;
  int K, N, bx, by;
  if (id < 4096) {
    int wsel = id >> 10, r = id & 1023;
    K = 1024; N = 1024; bx = r & 31; by = r >> 5;
    W = wsel == 0 ? Wq : (wsel == 1 ? Wk : (wsel == 2 ? Wv : Wo));
    Wt = wsel == 3 ? wt_o : wt_qkv + wsel * 1024 * 1024;
  } else if (id < 8192) {
    int r = id - 4096;
    K = 1024; N = 4096; bx = r & 127; by = r >> 7;
    W = W1; Wt = wt_1;
  } else {
    int r = id - 8192;
    K = 4096; N = 1024; bx = r & 31; by = r >> 5;
    W = W2; Wt = wt_2;
  }
  const int n0 = bx * 32, k0 = by * 32;
  const int tx = threadIdx.x & 31, ty = threadIdx.x >> 5;
#pragma unroll
  for (int i = 0; i < 32; i += 8)
    tile[ty + i][tx] = W[(size_t)(k0 + ty + i) * N + n0 + tx];
  __syncthreads();
#pragma unroll
  for (int i = 0; i < 32; i += 8)
    Wt[(size_t)(n0 + ty + i) * K + k0 + tx] = f2b(tile[tx][ty + i]);
}

// ---------------- GEMM v4: counted-vmcnt half-pipelined, 1 barrier/phase ---------------
#define MODE_QKV 0
#define MODE_RAWB 1
#define MODE_RELU 2

template <int BN, int MODE>
__global__ __launch_bounds__(512, 2) void k_gemm2(
    const uint16_t* __restrict__ A, const uint16_t* __restrict__ Bt, int M, int N, int K,
    int nx, const float* __restrict__ bias0, const float* __restrict__ bias1,
    const float* __restrict__ bias2, uint16_t* __restrict__ ob0, uint16_t* __restrict__ ob1,
    uint16_t* __restrict__ ob2, float* __restrict__ of) {
  constexpr int ASZ = 256 * 64;
  constexpr int BSZ = BN * 64;
  __shared__ __align__(16) uint16_t lds[2 * (ASZ + BSZ)];
  uint16_t* const Abase = lds;
  uint16_t* const Bbase = lds + 2 * ASZ;
  constexpr int WN = (BN == 256) ? 4 : 2;
  constexpr int MREP = (BN == 256) ? 8 : 4;
  constexpr int NPH = (BN == 256) ? 4 : 2;
  constexpr int MJ = (BN == 256) ? 4 : 2;  // A frags per phase
  constexpr int NJ = (BN == 256) ? 2 : 4;  // B frags per phase
  const int o = blockIdx.x;
  const int chunk = gridDim.x >> 3;
  const int wg = (o & 7) * chunk + (o >> 3);
  const int brow = (wg / nx) << 8;
  const int bcol = (wg % nx) * BN;
  const int t = threadIdx.x;
  const int wid = t >> 6, l = t & 63, g = l >> 4, lr = l & 15;
  const int wr = wid / WN, wc = wid % WN;

  auto rowb = [&](int m) {
    return (BN == 256) ? ((m >> 2) * 128 + wr * 64 + (m & 3) * 16)
                       : ((m >> 1) * 128 + wr * 32 + (m & 1) * 16);
  };
  auto colb = [&](int n) {
    return (BN == 256) ? ((n >> 1) * 128 + wc * 32 + (n & 1) * 16) : (wc * 64 + n * 16);
  };

  const int srow = t >> 3;
  const int ss0 = (t & 7) ^ (srow & 7);
  const int ss1 = (t & 7) ^ ((srow + 64) & 7);

  auto stage_half = [&](const uint16_t* gsrc, int grow0, int kk, uint16_t* ldst) {
    gload16(gsrc + (size_t)(grow0 + srow) * K + kk + ss0 * 8, ldst + t * 8);
    gload16(gsrc + (size_t)(grow0 + srow + 64) * K + kk + ss1 * 8, ldst + 4096 + t * 8);
  };
  auto rdfrag = [&](const uint16_t* buf, int ar, int kk) -> short8 {
    int slot = ((kk << 2) + g) ^ (ar & 7);
    return *reinterpret_cast<const short8*>(buf + ar * 64 + slot * 8);
  };

  f32x4 acc[MREP][4] = {};
  const int nt = K >> 6;

  // prologue: stage tile 0 in the steady-state order
  if (BN == 256) {
    stage_half(A, brow, 0, Abase);                // A0
    stage_half(Bt, bcol, 0, Bbase);               // B0
    stage_half(Bt, bcol + 128, 0, Bbase + 8192);  // B1
    stage_half(A, brow + 128, 0, Abase + 8192);   // A1
  } else {
    stage_half(A, brow, 0, Abase);               // A0
    stage_half(Bt, bcol, 0, Bbase);              // B (both halves, one call)
    stage_half(A, brow + 128, 0, Abase + 8192);  // A1
  }

  for (int kt = 0; kt < nt; ++kt) {
    const int cur = kt & 1;
    const uint16_t* Ac = Abase + cur * ASZ;
    const uint16_t* Bc = Bbase + cur * BSZ;
    uint16_t* An = Abase + (cur ^ 1) * ASZ;
    uint16_t* Bn = Bbase + (cur ^ 1) * BSZ;
    const bool pf = (kt + 1 < nt);
    const int knx = (kt + 1) << 6;
#pragma unroll
    for (int q = 0; q < NPH; ++q) {
      // --- counted wait + one barrier per phase ---
      if (BN == 256) {
        if (q == 0) {
          asm volatile("s_waitcnt vmcnt(4)" ::: "memory");
        } else if (q == 1) {
          if (pf) asm volatile("s_waitcnt vmcnt(4)" ::: "memory");
          else asm volatile("s_waitcnt vmcnt(2)" ::: "memory");
        } else if (q == 2) {
          if (pf) asm volatile("s_waitcnt vmcnt(4)" ::: "memory");
          else asm volatile("s_waitcnt vmcnt(0)" ::: "memory");
        }
      } else {
        if (q == 0) {
          asm volatile("s_waitcnt vmcnt(2)" ::: "memory");
        } else {
          if (pf) asm volatile("s_waitcnt vmcnt(4)" ::: "memory");
          else asm volatile("s_waitcnt vmcnt(0)" ::: "memory");
        }
      }
      __builtin_amdgcn_s_barrier();
      __builtin_amdgcn_sched_barrier(0);
      // --- stage next tile's half (uniform order across all threads) ---
      if (pf) {
        if (BN == 256) {
          if (q == 0) stage_half(A, brow, knx, An);
          else if (q == 1) stage_half(Bt, bcol, knx, Bn);
          else if (q == 2) stage_half(Bt, bcol + 128, knx, Bn + 8192);
          else stage_half(A, brow + 128, knx, An + 8192);
        } else {
          if (q == 0) {
            stage_half(A, brow, knx, An);
            stage_half(Bt, bcol, knx, Bn);
          } else {
            stage_half(A, brow + 128, knx, An + 8192);
          }
        }
      }
      // --- frag reads + MFMA ---
      const int mq = (BN == 256) ? (q >> 1) : q;
      const int nq = (BN == 256) ? (q & 1) : 0;
      short8 af[MJ][2], bf[NJ][2];
#pragma unroll
      for (int j = 0; j < MJ; ++j)
#pragma unroll
        for (int kk = 0; kk < 2; ++kk)
          af[j][kk] = rdfrag(Ac, rowb(mq * MJ + j) + lr, kk);
#pragma unroll
      for (int j2 = 0; j2 < NJ; ++j2)
#pragma unroll
        for (int kk = 0; kk < 2; ++kk)
          bf[j2][kk] = rdfrag(Bc, colb(nq * NJ + j2) + lr, kk);
      __builtin_amdgcn_s_setprio(1);
#pragma unroll
      for (int j = 0; j < MJ; ++j)
#pragma unroll
        for (int j2 = 0; j2 < NJ; ++j2)
#pragma unroll
          for (int kk = 0; kk < 2; ++kk)
            acc[mq * MJ + j][nq * NJ + j2] = __builtin_amdgcn_mfma_f32_16x16x32_bf16(
                af[j][kk], bf[j2][kk], acc[mq * MJ + j][nq * NJ + j2], 0, 0, 0);
      __builtin_amdgcn_s_setprio(0);
    }
  }

  // ---- epilogue ----
  if (MODE == MODE_QKV && bcol >= 2048) {
    // V block: bias, transpose via LDS (reuse), coalesced write to vt (ob2)
    const int dbase = bcol - 2048;
    __syncthreads();
#pragma unroll
    for (int m = 0; m < MREP; ++m) {
#pragma unroll
      for (int n = 0; n < 4; ++n) {
        const int cl = colb(n) + lr;
        const float bb = bias2[dbase + cl];
        uint16_t pk[4];
#pragma unroll
        for (int qi = 0; qi < 4; ++qi) pk[qi] = f2b(acc[m][n][qi] + bb);
        const int r0 = rowb(m) + g * 4;
        *reinterpret_cast<uint2*>(&lds[cl * 264 + r0]) = *reinterpret_cast<uint2*>(pk);
      }
    }
    __syncthreads();
    const int bV = brow >> 11;
    const int tt0 = brow & 2047;
#pragma unroll
    for (int j = 0; j < 8; ++j) {
      int ch = j * 512 + t;
      int dl = ch >> 5, sc = ch & 31;
      short8 vv = *reinterpret_cast<const short8*>(&lds[dl * 264 + sc * 8]);
      int hd = dbase + dl;
      int h2 = hd >> 6, d = hd & 63;
      *reinterpret_cast<short8*>(ob2 + ((size_t)(bV * NH + h2)) * SEQ * DKH + (size_t)d * SEQ +
                                 tt0 + sc * 8) = vv;
    }
    return;
  }
#pragma unroll
  for (int m = 0; m < MREP; ++m) {
#pragma unroll
    for (int n = 0; n < 4; ++n) {
#pragma unroll
      for (int qi = 0; qi < 4; ++qi) {
        int r = brow + rowb(m) + g * 4 + qi;
        int c = bcol + colb(n) + lr;
        float v = acc[m][n][qi];
        if (MODE == MODE_QKV) {  // Q or K block
          int which = c >> 10;
          int hd = c & 1023;
          const float* bp = which == 0 ? bias0 : bias1;
          v += bp[hd];
          if (which == 0) v *= 0.1803368801f;  // 1/sqrt(dk) * log2(e)
          uint16_t* dst = which == 0 ? ob0 : ob1;
          int b = r >> 11, tt = r & 2047;
          int h = hd >> 6, d = hd & 63;
          dst[((size_t)((b * NH + h) * SEQ + tt)) * DKH + d] = f2b(v);
        } else if (MODE == MODE_RELU) {
          v += bias0[c];
          v = fmaxf(v, 0.0f);
          ob0[(size_t)r * N + c] = f2b(v);
        } else {  // MODE_RAWB
          ob0[(size_t)r * N + c] = f2b(v);
        }
      }
    }
  }
}

// ---------------- attention: 32 q/wave, grid 1024, XCD-local; tree-sum l ---------------
__global__ __launch_bounds__(256) void k_attn(const uint16_t* __restrict__ Qb,
                                              const uint16_t* __restrict__ Kb,
                                              const uint16_t* __restrict__ Vtg,
                                              uint16_t* __restrict__ ctx) {
  __shared__ __align__(16) uint16_t Ks[2][64 * 64];
  __shared__ __align__(16) uint16_t Vs[2][64 * 64];
  __shared__ float l_arr[4][32];
  const int o = blockIdx.x;
  const int wg = (o & 7) * 128 + (o >> 3);
  const int qt = wg & 15;
  const int bh = wg >> 4;
  const int b = bh >> 4, h = bh & 15;
  const uint16_t* Qp = Qb + (size_t)bh * SEQ * DKH;
  const uint16_t* Kp = Kb + (size_t)bh * SEQ * DKH;
  const uint16_t* Vp = Vtg + (size_t)bh * SEQ * DKH;  // [64][2048]
  const int t = threadIdx.x, w = t >> 6, l = t & 63;
  const int lo5 = l & 31, hh = l >> 5;
  const int qbase = qt * 128 + w * 32;

  short8 qf[4];
#pragma unroll
  for (int kc = 0; kc < 4; ++kc)
    qf[kc] = *reinterpret_cast<const short8*>(Qp + (size_t)(qbase + lo5) * DKH + kc * 16 + hh * 8);

  f32x16 oacc[2] = {};
  float lsum = 0.f;

  const int swz = ((l & 7) ^ ((l >> 3) & 7)) << 3;
  const int ci0 = w * 2, ci1 = w * 2 + 1;
  const int r0 = ci0 * 8 + (l >> 3), r1 = ci1 * 8 + (l >> 3);
  uint16_t* ldsK0 = &Ks[0][0] + ci0 * 512 + l * 8;
  uint16_t* ldsK1 = &Ks[0][0] + ci1 * 512 + l * 8;
  uint16_t* ldsV0 = &Vs[0][0] + ci0 * 512 + l * 8;
  uint16_t* ldsV1 = &Vs[0][0] + ci1 * 512 + l * 8;
  const uint16_t* gK0 = Kp + (size_t)r0 * DKH + swz;
  const uint16_t* gK1 = Kp + (size_t)r1 * DKH + swz;
  const uint16_t* gV0 = Vp + (size_t)r0 * SEQ + swz;
  const uint16_t* gV1 = Vp + (size_t)r1 * SEQ + swz;

  gload16(gK0, ldsK0);
  gload16(gK1, ldsK1);
  gload16(gV0, ldsV0);
  gload16(gV1, ldsV1);
  __syncthreads();

  for (int tile = 0; tile < 32; ++tile) {
    const int cur = tile & 1;
    if (tile < 31) {
      const int nxt = (cur ^ 1) * 4096;
      const size_t s0n = (size_t)(tile + 1) * 64;
      gload16(gK0 + s0n * DKH, ldsK0 + nxt);
      gload16(gK1 + s0n * DKH, ldsK1 + nxt);
      gload16(gV0 + s0n, ldsV0 + nxt);
      gload16(gV1 + s0n, ldsV1 + nxt);
    }
    const char* Kbuf = reinterpret_cast<const char*>(&Ks[cur][0]);
    const char* Vbuf = reinterpret_cast<const char*>(&Vs[cur][0]);

#pragma unroll
    for (int sblk = 0; sblk < 2; ++sblk) {
      short8 kf[4];
      const int krow = sblk * 32 + lo5;
      const int kxor = (krow & 7) << 4;
#pragma unroll
      for (int kc = 0; kc < 4; ++kc) {
        int cb = (kc * 32 + hh * 16) ^ kxor;
        kf[kc] = *reinterpret_cast<const short8*>(Kbuf + krow * 128 + cb);
      }
      short8 vf[2][2];
#pragma unroll
      for (int scl = 0; scl < 2; ++scl)
#pragma unroll
        for (int dblk = 0; dblk < 2; ++dblk) {
          int vrow = dblk * 32 + lo5;
          int cb = (sblk * 64 + scl * 32 + hh * 16) ^ ((vrow & 7) << 4);
          vf[scl][dblk] = *reinterpret_cast<const short8*>(Vbuf + vrow * 128 + cb);
        }

      f32x16 sa = {};
      __builtin_amdgcn_s_setprio(1);
#pragma unroll
      for (int kc = 0; kc < 4; ++kc)
        sa = __builtin_amdgcn_mfma_f32_32x32x16_bf16(kf[kc], qf[kc], sa, 0, 0, 0);
      __builtin_amdgcn_s_setprio(0);

      float p[16];
#pragma unroll
      for (int r = 0; r < 16; ++r) p[r] = __builtin_amdgcn_exp2f(sa[r]);
      // pairwise tree sum: 4-level dependency chain instead of 16-deep serial adds
      {
        float s0 = (p[0] + p[1]) + (p[2] + p[3]);
        float s1 = (p[4] + p[5]) + (p[6] + p[7]);
        float s2 = (p[8] + p[9]) + (p[10] + p[11]);
        float s3 = (p[12] + p[13]) + (p[14] + p[15]);
        lsum += (s0 + s1) + (s2 + s3);
      }

      uint32_t clo[4], chi[4];
#pragma unroll
      for (int m = 0; m < 4; ++m) {
        asm("v_cvt_pk_bf16_f32 %0, %1, %2" : "=v"(clo[m]) : "v"(p[4 * m]), "v"(p[4 * m + 1]));
        asm("v_cvt_pk_bf16_f32 %0, %1, %2" : "=v"(chi[m]) : "v"(p[4 * m + 2]), "v"(p[4 * m + 3]));
      }

#pragma unroll
      for (int scl = 0; scl < 2; ++scl) {
        uint32_t a0 = clo[2 * scl], b0 = clo[2 * scl + 1];
        uint32_t a1 = chi[2 * scl], b1 = chi[2 * scl + 1];
        asm("v_permlane32_swap_b32 %0, %1" : "+v"(a0), "+v"(b0));
        asm("v_permlane32_swap_b32 %0, %1" : "+v"(a1), "+v"(b1));
        union {
          uint32_t u[4];
          short8 s;
        } pu;
        pu.u[0] = a0;
        pu.u[1] = a1;
        pu.u[2] = b0;
        pu.u[3] = b1;
        __builtin_amdgcn_s_setprio(1);
#pragma unroll
        for (int dblk = 0; dblk < 2; ++dblk)
          oacc[dblk] = __builtin_amdgcn_mfma_f32_32x32x16_bf16(pu.s, vf[scl][dblk], oacc[dblk], 0, 0, 0);
        __builtin_amdgcn_s_setprio(0);
      }
    }
    __syncthreads();
  }

  {
    float full = lsum + __shfl_xor(lsum, 32, 64);
    if (l < 32) l_arr[w][lo5] = full;
  }
#pragma unroll
  for (int r = 0; r < 16; ++r) {
    int q = (r & 3) + 8 * (r >> 2) + 4 * hh;
    float li = 1.0f / l_arr[w][q];
    int rowg = b * SEQ + qbase + q;
#pragma unroll
    for (int dblk = 0; dblk < 2; ++dblk) {
      int colg = h * DKH + dblk * 32 + lo5;
      ctx[(size_t)rowg * DMODEL + colg] = f2b(oacc[dblk][r] * li);
    }
  }
}

// ---------------- LayerNorm over (in + bias + res); in/res bf16-capable ----------------
template <bool WRITE_B, bool INBF, bool RESBF>
__global__ __launch_bounds__(256) void k_ln(const void* __restrict__ in,
                                            const float* __restrict__ bias,
                                            const void* __restrict__ res,
                                            const float* __restrict__ gam,
                                            const float* __restrict__ bet,
                                            float* __restrict__ outf,
                                            uint16_t* __restrict__ outb) {
  const int row = blockIdx.x;
  const int t = threadIdx.x, lane = t & 63, w = t >> 6;
  float4 v;
  if (INBF) {
    uint2 iu = reinterpret_cast<const uint2*>((const uint16_t*)in + (size_t)row * DMODEL)[t];
    const uint16_t* ip = reinterpret_cast<const uint16_t*>(&iu);
    v.x = b2f(ip[0]); v.y = b2f(ip[1]); v.z = b2f(ip[2]); v.w = b2f(ip[3]);
  } else {
    v = reinterpret_cast<const float4*>((const float*)in + (size_t)row * DMODEL)[t];
  }
  float4 bb0 = reinterpret_cast<const float4*>(bias)[t];
  float4 rr;
  if (RESBF) {
    uint2 ru = reinterpret_cast<const uint2*>((const uint16_t*)res + (size_t)row * DMODEL)[t];
    const uint16_t* rp = reinterpret_cast<const uint16_t*>(&ru);
    rr.x = b2f(rp[0]); rr.y = b2f(rp[1]); rr.z = b2f(rp[2]); rr.w = b2f(rp[3]);
  } else {
    rr = reinterpret_cast<const float4*>((const float*)res + (size_t)row * DMODEL)[t];
  }
  v.x += bb0.x + rr.x;
  v.y += bb0.y + rr.y;
  v.z += bb0.z + rr.z;
  v.w += bb0.w + rr.w;
  float s = v.x + v.y + v.z + v.w;
  float s2 = v.x * v.x + v.y * v.y + v.z * v.z + v.w * v.w;
#pragma unroll
  for (int off = 1; off < 64; off <<= 1) {
    s += __shfl_xor(s, off, 64);
    s2 += __shfl_xor(s2, off, 64);
  }
  __shared__ float rs[4], rq[4];
  if (lane == 0) {
    rs[w] = s;
    rq[w] = s2;
  }
  __syncthreads();
  float ts = rs[0] + rs[1] + rs[2] + rs[3];
  float tq = rq[0] + rq[1] + rq[2] + rq[3];
  const float inv = 1.0f / DMODEL;
  float mu = ts * inv;
  float var = tq * inv - mu * mu;
  float rstd = rsqrtf(var + 1e-5f);
  float4 gg = reinterpret_cast<const float4*>(gam)[t];
  float4 bb = reinterpret_cast<const float4*>(bet)[t];
  float4 y;
  y.x = (v.x - mu) * rstd * gg.x + bb.x;
  y.y = (v.y - mu) * rstd * gg.y + bb.y;
  y.z = (v.z - mu) * rstd * gg.z + bb.z;
  y.w = (v.w - mu) * rstd * gg.w + bb.w;
  if (WRITE_B) {
    uint16_t oo[4] = {f2b(y.x), f2b(y.y), f2b(y.z), f2b(y.w)};
    reinterpret_cast<uint2*>(outb)[(size_t)row * 256 + t] = *reinterpret_cast<uint2*>(oo);
  } else {
    reinterpret_cast<float4*>(outf)[(size_t)row * 256 + t] = y;
  }
}

extern "C" void kernel_launch(void* const* d_in, const int* in_sizes, int n_in, void* d_out,
                              int out_size, void* d_ws, size_t ws_size, hipStream_t stream) {
  const float* x = (const float*)d_in[0];
  const float* Wq = (const float*)d_in[1];
  const float* bq = (const float*)d_in[2];
  const float* Wk = (const float*)d_in[3];
  const float* bk = (const float*)d_in[4];
  const float* Wv = (const float*)d_in[5];
  const float* bv = (const float*)d_in[6];
  const float* Wo = (const float*)d_in[7];
  const float* bo = (const float*)d_in[8];
  const float* g1 = (const float*)d_in[9];
  const float* be1 = (const float*)d_in[10];
  const float* W1 = (const float*)d_in[11];
  const float* b1 = (const float*)d_in[12];
  const float* W2 = (const float*)d_in[13];
  const float* b2 = (const float*)d_in[14];
  const float* g2 = (const float*)d_in[15];
  const float* be2 = (const float*)d_in[16];

  char* ws = (char*)d_ws;
  size_t off = 0;
  auto alloc = [&](size_t bytes) {
    char* p = ws + off;
    off += (bytes + 255) & ~(size_t)255;
    return p;
  };
  uint16_t* wt_qkv = (uint16_t*)alloc(3072ull * 1024 * 2);
  uint16_t* wt_o = (uint16_t*)alloc(1024ull * 1024 * 2);
  uint16_t* wt_1 = (uint16_t*)alloc(4096ull * 1024 * 2);
  uint16_t* wt_2 = (uint16_t*)alloc(1024ull * 4096 * 2);
  uint16_t* xb = (uint16_t*)alloc(8192ull * 1024 * 2);     // x bf16 (live: LN1 residual)
  uint16_t* ctx = (uint16_t*)alloc(8192ull * 1024 * 2);    // attention output
  uint16_t* bfout = (uint16_t*)alloc(8192ull * 1024 * 2);  // Wo out bf16, then FFN2 out bf16
  uint16_t* vt = (uint16_t*)alloc(8192ull * 1024 * 2);     // V^T (written by QKV epilogue)
  char* big = alloc(16777216ull + 67108864ull);            // Q(16)+K(16) -> x1b(16)+h(64)
  uint16_t* Qbuf = (uint16_t*)big;
  uint16_t* Kbuf = (uint16_t*)(big + 16777216ull);
  uint16_t* x1b = (uint16_t*)big;                   // alias: Q dead after attention
  uint16_t* hbuf = (uint16_t*)(big + 16777216ull);  // alias: K dead after attention
  (void)ws_size;

  // 1. all prep (weight transposes + x cast) in one launch
  k_prep<<<20480, 256, 0, stream>>>(Wq, Wk, Wv, Wo, W1, W2, x, wt_qkv, wt_o, wt_1, wt_2, xb);
  // 2. QKV projection; V written pre-transposed into vt by the fused epilogue
  k_gemm2<128, MODE_QKV><<<768, 512, 0, stream>>>(
      xb, wt_qkv, 8192, 3072, 1024, 24, bq, bk, bv, Qbuf, Kbuf, vt, nullptr);
  // 3. attention -> ctx
  k_attn<<<1024, 256, 0, stream>>>(Qbuf, Kbuf, vt, ctx);
  // 4. Wo projection -> bfout (bf16)
  k_gemm2<128, MODE_RAWB><<<256, 512, 0, stream>>>(
      ctx, wt_o, 8192, 1024, 1024, 8, nullptr, nullptr, nullptr, bfout, nullptr, nullptr, nullptr);
  // 5. LN1(bfout + bo + xb) -> x1b (bf16)
  k_ln<true, true, true><<<8192, 256, 0, stream>>>(bfout, bo, xb, g1, be1, nullptr, x1b);
  // 6. FFN1: relu(x1 @ W1 + b1) -> h bf16
  k_gemm2<256, MODE_RELU><<<512, 512, 0, stream>>>(
      x1b, wt_1, 8192, 4096, 1024, 16, b1, nullptr, nullptr, hbuf, nullptr, nullptr, nullptr);
  // 7. FFN2 -> bfout (bf16)
  k_gemm2<128, MODE_RAWB><<<256, 512, 0, stream>>>(
      hbuf, wt_2, 8192, 1024, 4096, 8, nullptr, nullptr, nullptr, bfout, nullptr, nullptr, nullptr);
  // 8. LN2(bfout + b2 + x1b) -> output (f32)
  k_ln<false, true, true><<<8192, 256, 0, stream>>>(bfout, b2, x1b, g2, be2, (float*)d_out, nullptr);
}